// Round 1
// baseline (5119.777 us; speedup 1.0000x reference)
//
#include <hip/hip_runtime.h>
#include <math.h>

// Problem constants (reference: S=2048, B=16, F=100, E=512, NH=8, DH=64,
// FF=2048, DEC=1024, H=512, NOUT=10, sep=1024 structurally).
#define SEP   1024
#define EVALN 1024
#define BB    16
#define FIN   100
#define EE    512
#define NHH   8
#define DHH   64
#define FFNN  2048
#define DECN  1024
#define HHN   512
#define NOUTN 10
#define TBR   (SEP * BB)   // 16384 token rows

__device__ __forceinline__ float nan2num(float v) {
  if (isnan(v)) return 0.f;
  if (isinf(v)) return v > 0.f ? 3.4028234663852886e38f : -3.4028234663852886e38f;
  return v;
}

// ---------------------------------------------------------------------------
// train_x[t,b,e] = y[t,b]*yenc_W[e] + yenc_b[e] + enc_b[e]   (GEMM accumulates
// x @ enc_W on top afterwards)
// ---------------------------------------------------------------------------
__global__ __launch_bounds__(256)
void prefill_kernel(const float* __restrict__ y, const float* __restrict__ yW,
                    const float* __restrict__ yb, const float* __restrict__ eb,
                    float* __restrict__ tx) {
  const int idx = blockIdx.x * 256 + threadIdx.x;   // < TBR*EE
  const int e = idx & (EE - 1);
  const int tb = idx >> 9;
  tx[idx] = fmaf(y[tb], yW[e], yb[e] + eb[e]);
}

// ---------------------------------------------------------------------------
// fp32 tiled GEMM: C[M,N] (+)= A[M,K] @ B[K,N] (+bias) (relu)
// 128x128 block tile, BK=16, 256 threads, 8x8 micro-tile (split 4+4 so LDS
// fragment reads alias only 2-way = free).  M,N must be multiples of 128.
// ---------------------------------------------------------------------------
template <bool ACC, bool BIAS, bool RELU>
__global__ __launch_bounds__(256)
void gemm_f32(const float* __restrict__ A, const float* __restrict__ B,
              float* __restrict__ C, const float* __restrict__ bias,
              int M, int N, int K) {
  __shared__ float As[16][128];  // As[k][m] (transposed)
  __shared__ float Bs[16][128];  // Bs[k][n]
  const int tid = threadIdx.x;
  const int n0 = blockIdx.x * 128;
  const int m0 = blockIdx.y * 128;
  const int tx = tid & 15;       // n-group
  const int ty = tid >> 4;       // m-group
  const int am = tid >> 1;       // A stage: row 0..127
  const int ak = (tid & 1) << 3; // A stage: k offset 0 or 8
  const int bk = tid >> 4;       // B stage: k row 0..15
  const int bn = (tid & 15) << 3;
  float c[8][8];
#pragma unroll
  for (int i = 0; i < 8; ++i)
#pragma unroll
    for (int j = 0; j < 8; ++j) c[i][j] = 0.f;

  for (int k0 = 0; k0 < K; k0 += 16) {
    // stage A (transpose into As[k][m])
    {
      const float* ap = A + (size_t)(m0 + am) * K + k0 + ak;
      float4 alo = {0, 0, 0, 0}, ahi = {0, 0, 0, 0};
      if (k0 + ak + 7 < K) {
        alo = *(const float4*)ap;
        ahi = *(const float4*)(ap + 4);
      } else {
        const int kb = k0 + ak;
        if (kb + 0 < K) alo.x = ap[0];
        if (kb + 1 < K) alo.y = ap[1];
        if (kb + 2 < K) alo.z = ap[2];
        if (kb + 3 < K) alo.w = ap[3];
        if (kb + 4 < K) ahi.x = ap[4];
        if (kb + 5 < K) ahi.y = ap[5];
        if (kb + 6 < K) ahi.z = ap[6];
        if (kb + 7 < K) ahi.w = ap[7];
      }
      As[ak + 0][am] = alo.x; As[ak + 1][am] = alo.y;
      As[ak + 2][am] = alo.z; As[ak + 3][am] = alo.w;
      As[ak + 4][am] = ahi.x; As[ak + 5][am] = ahi.y;
      As[ak + 6][am] = ahi.z; As[ak + 7][am] = ahi.w;
    }
    // stage B
    {
      float4 blo = {0, 0, 0, 0}, bhi = {0, 0, 0, 0};
      if (k0 + bk < K) {
        const float* bp = B + (size_t)(k0 + bk) * N + n0 + bn;
        blo = *(const float4*)bp;
        bhi = *(const float4*)(bp + 4);
      }
      *(float4*)&Bs[bk][bn] = blo;
      *(float4*)&Bs[bk][bn + 4] = bhi;
    }
    __syncthreads();
#pragma unroll
    for (int kk = 0; kk < 16; ++kk) {
      float4 a0 = *(const float4*)&As[kk][ty << 2];
      float4 a1 = *(const float4*)&As[kk][64 + (ty << 2)];
      float4 b0 = *(const float4*)&Bs[kk][tx << 2];
      float4 b1 = *(const float4*)&Bs[kk][64 + (tx << 2)];
      float ar[8] = {a0.x, a0.y, a0.z, a0.w, a1.x, a1.y, a1.z, a1.w};
      float br[8] = {b0.x, b0.y, b0.z, b0.w, b1.x, b1.y, b1.z, b1.w};
#pragma unroll
      for (int i = 0; i < 8; ++i)
#pragma unroll
        for (int j = 0; j < 8; ++j) c[i][j] = fmaf(ar[i], br[j], c[i][j]);
    }
    __syncthreads();
  }
  // epilogue
  float4 bz0 = {0, 0, 0, 0}, bz1 = {0, 0, 0, 0};
  if (BIAS) {
    bz0 = *(const float4*)(bias + n0 + (tx << 2));
    bz1 = *(const float4*)(bias + n0 + 64 + (tx << 2));
  }
#pragma unroll
  for (int i = 0; i < 8; ++i) {
    const int ml = (i < 4) ? ((ty << 2) + i) : (64 + (ty << 2) + i - 4);
    float* cp = C + (size_t)(m0 + ml) * N + n0 + (tx << 2);
    float4 v0 = {c[i][0], c[i][1], c[i][2], c[i][3]};
    float4 v1 = {c[i][4], c[i][5], c[i][6], c[i][7]};
    if (BIAS) {
      v0.x += bz0.x; v0.y += bz0.y; v0.z += bz0.z; v0.w += bz0.w;
      v1.x += bz1.x; v1.y += bz1.y; v1.z += bz1.z; v1.w += bz1.w;
    }
    if (ACC) {
      float4 p0 = *(const float4*)cp;
      float4 p1 = *(const float4*)(cp + 64);
      v0.x += p0.x; v0.y += p0.y; v0.z += p0.z; v0.w += p0.w;
      v1.x += p1.x; v1.y += p1.y; v1.z += p1.z; v1.w += p1.w;
    }
    if (RELU) {
      v0.x = fmaxf(v0.x, 0.f); v0.y = fmaxf(v0.y, 0.f);
      v0.z = fmaxf(v0.z, 0.f); v0.w = fmaxf(v0.w, 0.f);
      v1.x = fmaxf(v1.x, 0.f); v1.y = fmaxf(v1.y, 0.f);
      v1.z = fmaxf(v1.z, 0.f); v1.w = fmaxf(v1.w, 0.f);
    }
    *(float4*)cp = v0;
    *(float4*)(cp + 64) = v1;
  }
}

// ---------------------------------------------------------------------------
// Attention: one block = (b, h, 8 t-rows).  QK^T with K staged d-sliced and
// transposed in LDS (contiguous b128 reads), full score rows in LDS, softmax
// via 32-lane shuffles, then PV from global V.
// Q,K,V,O layout: [T, B, NH, DH] flat == [(t*B+b)*E + h*64 + d].
// ---------------------------------------------------------------------------
__global__ __launch_bounds__(256)
void attn_f32(const float* __restrict__ Q, const float* __restrict__ K,
              const float* __restrict__ V, float* __restrict__ O) {
  __shared__ float qs[8][68];      // q rows, padded
  __shared__ float kds[4][SEP];    // K d-slice, transposed: kds[dd][s]
  __shared__ float sc[8][1028];    // score rows (pad keeps 16B align, 2-way max)
  const int tid = threadIdx.x;
  const int t0 = blockIdx.x << 3;
  const int h = blockIdx.y;
  const int b = blockIdx.z;
  if (tid < 128) {
    const int r = tid >> 4;
    const int d4 = (tid & 15) << 2;
    *(float4*)&qs[r][d4] =
        *(const float4*)(Q + ((size_t)(t0 + r) * BB + b) * EE + h * DHH + d4);
  }
  float c[8][4];
#pragma unroll
  for (int t = 0; t < 8; ++t)
#pragma unroll
    for (int j = 0; j < 4; ++j) c[t][j] = 0.f;
  __syncthreads();
  // thread owns s-cols 4*tid..4*tid+3 for all 8 t-rows
  for (int d4 = 0; d4 < 16; ++d4) {
    for (int j = tid; j < SEP; j += 256) {
      float4 kv = *(const float4*)(K + ((size_t)j * BB + b) * EE + h * DHH + (d4 << 2));
      kds[0][j] = kv.x; kds[1][j] = kv.y; kds[2][j] = kv.z; kds[3][j] = kv.w;
    }
    __syncthreads();
    float qarr[8][4];
#pragma unroll
    for (int t = 0; t < 8; ++t)
      *(float4*)qarr[t] = *(const float4*)&qs[t][d4 << 2];
#pragma unroll
    for (int dd = 0; dd < 4; ++dd) {
      float4 k4 = *(const float4*)&kds[dd][tid << 2];
#pragma unroll
      for (int t = 0; t < 8; ++t) {
        const float qv = qarr[t][dd];
        c[t][0] = fmaf(qv, k4.x, c[t][0]);
        c[t][1] = fmaf(qv, k4.y, c[t][1]);
        c[t][2] = fmaf(qv, k4.z, c[t][2]);
        c[t][3] = fmaf(qv, k4.w, c[t][3]);
      }
    }
    __syncthreads();
  }
#pragma unroll
  for (int t = 0; t < 8; ++t) {
    float4 v4 = {c[t][0] * 0.125f, c[t][1] * 0.125f,
                 c[t][2] * 0.125f, c[t][3] * 0.125f};
    *(float4*)&sc[t][tid << 2] = v4;
  }
  __syncthreads();
  // softmax: 32 threads per t-row
  const int row = tid >> 5;
  const int sl = tid & 31;
  float mx = -1e30f;
  for (int s = sl; s < SEP; s += 32) mx = fmaxf(mx, sc[row][s]);
#pragma unroll
  for (int off = 16; off >= 1; off >>= 1) mx = fmaxf(mx, __shfl_xor(mx, off));
  float sum = 0.f;
  for (int s = sl; s < SEP; s += 32) {
    const float p = __expf(sc[row][s] - mx);
    sc[row][s] = p;
    sum += p;
  }
#pragma unroll
  for (int off = 16; off >= 1; off >>= 1) sum += __shfl_xor(sum, off);
  const float inv = 1.f / sum;
  __syncthreads();
  // PV: thread (row, sl) owns d = 2*sl, 2*sl+1
  float2 acc = {0.f, 0.f};
  const float* vp = V + (size_t)b * EE + h * DHH + (sl << 1);
  for (int s = 0; s < SEP; s += 4) {
    float4 p4 = *(const float4*)&sc[row][s];
    float2 v0 = *(const float2*)(vp + (size_t)(s + 0) * (BB * EE));
    float2 v1 = *(const float2*)(vp + (size_t)(s + 1) * (BB * EE));
    float2 v2 = *(const float2*)(vp + (size_t)(s + 2) * (BB * EE));
    float2 v3 = *(const float2*)(vp + (size_t)(s + 3) * (BB * EE));
    acc.x = fmaf(p4.x, v0.x, acc.x); acc.y = fmaf(p4.x, v0.y, acc.y);
    acc.x = fmaf(p4.y, v1.x, acc.x); acc.y = fmaf(p4.y, v1.y, acc.y);
    acc.x = fmaf(p4.z, v2.x, acc.x); acc.y = fmaf(p4.z, v2.y, acc.y);
    acc.x = fmaf(p4.w, v3.x, acc.x); acc.y = fmaf(p4.w, v3.y, acc.y);
  }
  float2 o2 = {acc.x * inv, acc.y * inv};
  *(float2*)(O + ((size_t)(t0 + row) * BB + b) * EE + h * DHH + (sl << 1)) = o2;
}

// ---------------------------------------------------------------------------
// LayerNorm over last dim (512): o[row] = LN(a[row] + r[row]) * g + be
// One 256-thread block per row; safe when o aliases r (reads precede writes).
// ---------------------------------------------------------------------------
__global__ __launch_bounds__(256)
void ln_f32(const float* __restrict__ a, const float* __restrict__ r,
            const float* __restrict__ g, const float* __restrict__ be,
            float* __restrict__ o) {
  __shared__ float ss[4], sqs[4];
  const int row = blockIdx.x;
  const int tid = threadIdx.x;
  const size_t base = (size_t)row * EE;
  const float x0 = a[base + tid] + r[base + tid];
  const float x1 = a[base + tid + 256] + r[base + tid + 256];
  float s = x0 + x1;
  float sq = x0 * x0 + x1 * x1;
#pragma unroll
  for (int off = 32; off >= 1; off >>= 1) {
    s += __shfl_xor(s, off);
    sq += __shfl_xor(sq, off);
  }
  const int wid = tid >> 6;
  if ((tid & 63) == 0) { ss[wid] = s; sqs[wid] = sq; }
  __syncthreads();
  s = ss[0] + ss[1] + ss[2] + ss[3];
  sq = sqs[0] + sqs[1] + sqs[2] + sqs[3];
  const float mean = s * (1.f / 512.f);
  const float var = sq * (1.f / 512.f) - mean * mean;
  const float rstd = rsqrtf(fmaxf(var, 0.f) + 1e-5f);
  o[base + tid] = (x0 - mean) * rstd * g[tid] + be[tid];
  o[base + tid + 256] = (x1 - mean) * rstd * g[tid + 256] + be[tid + 256];
}

// pooled[b*E+e] = mean over t of out[t,b,e]
__global__ __launch_bounds__(256)
void pool_f32(const float* __restrict__ outb, float* __restrict__ pooled) {
  const int i = blockIdx.x * 256 + threadIdx.x;  // < B*E
  float s = 0.f;
  for (int t = 0; t < SEP; ++t) s += outb[(size_t)t * (BB * EE) + i];
  pooled[i] = s * (1.f / (float)SEP);
}

// dh[b,n] = relu(pooled[b,:] @ dec_W[:,n] + dec_b[n])
__global__ __launch_bounds__(256)
void dec_f32(const float* __restrict__ pooled, const float* __restrict__ dW,
             const float* __restrict__ db, float* __restrict__ dh) {
  const int n = blockIdx.x * 256 + threadIdx.x;  // < DEC
  const int b = blockIdx.y;
  const float* pp = pooled + b * EE;
  float acc = db[n];
  for (int k = 0; k < EE; ++k) acc = fmaf(pp[k], dW[(size_t)k * DECN + n], acc);
  dh[b * DECN + n] = fmaxf(acc, 0.f);
}

// C[b, n] = dh[b, :] @ W[:, n]   (K = DEC = 1024, all 16 b per thread)
__global__ __launch_bounds__(256)
void headgemm(const float* __restrict__ dh, const float* __restrict__ W,
              float* __restrict__ C, int N) {
  __shared__ float ds[16][128];
  const int n = blockIdx.x * 256 + threadIdx.x;
  float acc[16];
#pragma unroll
  for (int i = 0; i < 16; ++i) acc[i] = 0.f;
  for (int k0 = 0; k0 < DECN; k0 += 128) {
    __syncthreads();
    for (int i = threadIdx.x; i < 2048; i += 256)
      ds[i >> 7][i & 127] = dh[(size_t)(i >> 7) * DECN + k0 + (i & 127)];
    __syncthreads();
    if (n < N) {
      for (int kk = 0; kk < 128; ++kk) {
        const float w = W[(size_t)(k0 + kk) * N + n];
#pragma unroll
        for (int bb = 0; bb < 16; ++bb) acc[bb] = fmaf(ds[bb][kk], w, acc[bb]);
      }
    }
  }
  if (n < N) {
#pragma unroll
    for (int bb = 0; bb < 16; ++bb) C[(size_t)bb * N + n] = acc[bb];
  }
}

// h1[e,b,h] = relu(nan2num(x[sep+e,b,:]) @ w1[b,:,h] + b1[b,h])
__global__ __launch_bounds__(256)
void eval1_kernel(const float* __restrict__ x, const float* __restrict__ w1,
                  const float* __restrict__ b1, float* __restrict__ h1) {
  __shared__ float xs[8][100];
  const int b = blockIdx.z;
  const int e0 = blockIdx.y << 3;
  const int hcol = blockIdx.x * 256 + threadIdx.x;
  for (int i = threadIdx.x; i < 800; i += 256) {
    const int ee = i / 100, f = i - ee * 100;
    xs[ee][f] = nan2num(x[((size_t)(SEP + e0 + ee) * BB + b) * FIN + f]);
  }
  __syncthreads();
  float acc[8];
#pragma unroll
  for (int i = 0; i < 8; ++i) acc[i] = 0.f;
  for (int f = 0; f < FIN; ++f) {
    const float w = w1[(size_t)b * (FIN * HHN) + (size_t)f * HHN + hcol];
#pragma unroll
    for (int ee = 0; ee < 8; ++ee) acc[ee] = fmaf(xs[ee][f], w, acc[ee]);
  }
  const float bias = b1[b * HHN + hcol];
#pragma unroll
  for (int ee = 0; ee < 8; ++ee)
    h1[((size_t)(e0 + ee) * BB + b) * HHN + hcol] = fmaxf(acc[ee] + bias, 0.f);
}

// out[e,b,o] = h1[e,b,:] @ w2[b,:,o] + b2[b,o]
__global__ __launch_bounds__(256)
void eval2_kernel(const float* __restrict__ h1, const float* __restrict__ w2,
                  const float* __restrict__ b2, float* __restrict__ outp) {
  const int idx = blockIdx.x * 256 + threadIdx.x;  // < EVALN*BB*NOUT
  const int o = idx % NOUTN;
  const int eb = idx / NOUTN;
  const int b = eb & (BB - 1);
  const float* hp = h1 + (size_t)eb * HHN;
  const float* wp = w2 + (size_t)b * (HHN * NOUTN) + o;
  float acc = b2[b * NOUTN + o];
  for (int k = 0; k < HHN; ++k) acc = fmaf(hp[k], wp[(size_t)k * NOUTN], acc);
  outp[idx] = acc;
}

// ---------------------------------------------------------------------------
extern "C" void kernel_launch(void* const* d_in, const int* in_sizes, int n_in,
                              void* d_out, int out_size, void* d_ws, size_t ws_size,
                              hipStream_t stream) {
  const float* x      = (const float*)d_in[0];
  const float* y      = (const float*)d_in[1];
  const float* enc_W  = (const float*)d_in[2];
  const float* enc_b  = (const float*)d_in[3];
  const float* yenc_W = (const float*)d_in[4];
  const float* yenc_b = (const float*)d_in[5];
  const float* Wq     = (const float*)d_in[6];
  const float* Wk     = (const float*)d_in[7];
  const float* Wv     = (const float*)d_in[8];
  const float* Wo     = (const float*)d_in[9];
  const float* ln1_g  = (const float*)d_in[10];
  const float* ln1_b  = (const float*)d_in[11];
  const float* ln2_g  = (const float*)d_in[12];
  const float* ln2_b  = (const float*)d_in[13];
  const float* ffn_W1 = (const float*)d_in[14];
  const float* ffn_b1 = (const float*)d_in[15];
  const float* ffn_W2 = (const float*)d_in[16];
  const float* ffn_b2 = (const float*)d_in[17];
  const float* dec_W  = (const float*)d_in[18];
  const float* dec_b  = (const float*)d_in[19];
  const float* hw1    = (const float*)d_in[20];
  const float* hb1    = (const float*)d_in[21];
  const float* hw2    = (const float*)d_in[22];
  const float* hb2    = (const float*)d_in[23];
  // d_in[24] = single_eval_pos (structurally 1024, hard-coded in grids)

  float* ws = (float*)d_ws;
  const size_t TBE = (size_t)TBR * EE;  // 8388608 floats per [T,B,E] buffer
  // Workspace layout (~196 MiB), with buffer reuse:
  float* trainx = ws;             // off0: train_x -> later ff2 -> out
  float* qb     = ws + 1 * TBE;   // off1: q -> later z -> later h1
  float* kb     = ws + 2 * TBE;   // off2: k -> later ff1 (spans off2..off5)
  float* vb     = ws + 3 * TBE;   // off3: v
  float* ao     = ws + 4 * TBE;   // off4: attention output
  float* aop    = ws + 5 * TBE;   // off5: ao @ Wo
  float* smal   = ws + 6 * TBE;   // small buffers
  float* pooled = smal;                         // 16*512
  float* dh     = pooled + BB * EE;             // 16*1024
  float* w1g    = dh + BB * DECN;               // 16*51200
  float* b1g    = w1g + (size_t)BB * FIN * HHN; // 16*512
  float* w2g    = b1g + BB * HHN;               // 16*5120
  float* b2g    = w2g + BB * HHN * NOUTN;       // 16*10
  float* z    = qb;
  float* ff1  = kb;
  float* ff2  = trainx;
  float* outb = trainx;
  float* h1   = qb;
  float* outp = (float*)d_out;

  // 1) train_x = y_src + biases; then += x @ enc_W
  prefill_kernel<<<(int)(TBE / 256), 256, 0, stream>>>(y, yenc_W, yenc_b, enc_b, trainx);
  gemm_f32<true, false, false><<<dim3(EE / 128, TBR / 128), 256, 0, stream>>>(
      x, enc_W, trainx, nullptr, TBR, EE, FIN);
  // 2) Q, K, V
  gemm_f32<false, false, false><<<dim3(EE / 128, TBR / 128), 256, 0, stream>>>(
      trainx, Wq, qb, nullptr, TBR, EE, EE);
  gemm_f32<false, false, false><<<dim3(EE / 128, TBR / 128), 256, 0, stream>>>(
      trainx, Wk, kb, nullptr, TBR, EE, EE);
  gemm_f32<false, false, false><<<dim3(EE / 128, TBR / 128), 256, 0, stream>>>(
      trainx, Wv, vb, nullptr, TBR, EE, EE);
  // 3) attention
  attn_f32<<<dim3(SEP / 8, NHH, BB), 256, 0, stream>>>(qb, kb, vb, ao);
  // 4) Wo projection + LN1
  gemm_f32<false, false, false><<<dim3(EE / 128, TBR / 128), 256, 0, stream>>>(
      ao, Wo, aop, nullptr, TBR, EE, EE);
  ln_f32<<<TBR, 256, 0, stream>>>(trainx, aop, ln1_g, ln1_b, z);
  // 5) FFN + LN2
  gemm_f32<false, true, true><<<dim3(FFNN / 128, TBR / 128), 256, 0, stream>>>(
      z, ffn_W1, ff1, ffn_b1, TBR, FFNN, EE);
  gemm_f32<false, true, false><<<dim3(EE / 128, TBR / 128), 256, 0, stream>>>(
      ff1, ffn_W2, ff2, ffn_b2, TBR, EE, FFNN);
  ln_f32<<<TBR, 256, 0, stream>>>(z, ff2, ln2_g, ln2_b, outb);
  // 6) decoder + per-batch head weights
  pool_f32<<<(BB * EE) / 256, 256, 0, stream>>>(outb, pooled);
  dec_f32<<<dim3(DECN / 256, BB), 256, 0, stream>>>(pooled, dec_W, dec_b, dh);
  headgemm<<<(FIN * HHN) / 256, 256, 0, stream>>>(dh, hw1, w1g, FIN * HHN);
  headgemm<<<HHN / 256, 256, 0, stream>>>(dh, hb1, b1g, HHN);
  headgemm<<<(HHN * NOUTN) / 256, 256, 0, stream>>>(dh, hw2, w2g, HHN * NOUTN);
  headgemm<<<1, 256, 0, stream>>>(dh, hb2, b2g, NOUTN);
  // 7) generated per-batch MLP on eval tokens
  eval1_kernel<<<dim3(HHN / 256, EVALN / 8, BB), 256, 0, stream>>>(x, w1g, b1g, h1);
  eval2_kernel<<<(EVALN * BB * NOUTN) / 256, 256, 0, stream>>>(h1, w2g, b2g, outp);
}

// Round 2
// 1768.525 us; speedup vs baseline: 2.8949x; 2.8949x over previous
//
#include <hip/hip_runtime.h>
#include <math.h>

// Problem constants: S=2048, B=16, F=100, E=512, NH=8, DH=64, FF=2048,
// DEC=1024, H=512, NOUT=10, sep=1024 (structural).
#define SEP   1024
#define EVALN 1024
#define BB    16
#define FIN   100
#define FINP  128          // F padded to 128 for bf16 GEMM (zeros)
#define EE    512
#define NHH   8
#define DHH   64
#define FFNN  2048
#define DECN  1024
#define HHN   512
#define NOUTN 10
#define TBR   (SEP * BB)   // 16384 token rows
#define MB    (1024u * 1024u)

typedef short  s16x8 __attribute__((ext_vector_type(8)));
typedef float  f32x4 __attribute__((ext_vector_type(4)));

__device__ __forceinline__ unsigned short f2b(float f) {
  union { float f; unsigned int u; } v; v.f = f;
  unsigned int u = v.u;
  return (unsigned short)((u + 0x7fffu + ((u >> 16) & 1u)) >> 16);
}

__device__ __forceinline__ float nan2num(float v) {
  if (isnan(v)) return 0.f;
  if (isinf(v)) return v > 0.f ? 3.4028234663852886e38f : -3.4028234663852886e38f;
  return v;
}

// ---------------------------------------------------------------------------
// Weight transpose+cast: W[K][N] f32 -> Wt[N][Kp] bf16 (zero-padded K..Kp).
// grid (N/32, Kp/32), block (32,8).
// ---------------------------------------------------------------------------
__global__ __launch_bounds__(256)
void transcast(const float* __restrict__ W, unsigned short* __restrict__ Wt,
               int K, int N, int Kp) {
  __shared__ float t[32][33];
  const int n0 = blockIdx.x * 32, k0 = blockIdx.y * 32;
  const int tx = threadIdx.x, ty = threadIdx.y;
#pragma unroll
  for (int r = 0; r < 4; ++r) {
    const int k = k0 + ty + r * 8;
    t[ty + r * 8][tx] = (k < K) ? W[(size_t)k * N + n0 + tx] : 0.f;
  }
  __syncthreads();
#pragma unroll
  for (int r = 0; r < 4; ++r) {
    const int n = n0 + ty + r * 8;
    Wt[(size_t)n * Kp + k0 + tx] = f2b(t[tx][ty + r * 8]);
  }
}

// x[:sep] f32 [16384][100] -> xb bf16 [16384][128] (zero-padded)
__global__ __launch_bounds__(256)
void castx_kernel(const float* __restrict__ x, unsigned short* __restrict__ xb) {
  const int idx = blockIdx.x * 256 + threadIdx.x;  // < 16384*128
  const int m = idx >> 7, f = idx & 127;
  xb[idx] = (f < FIN) ? f2b(x[(size_t)m * FIN + f]) : (unsigned short)0;
}

// ---------------------------------------------------------------------------
// bf16 MFMA GEMM: C[M,N] = A[M,K](bf16) @ Bt[N,K](bf16)^T  + epilogue.
// 128x128 tile, BK=32, 256 threads (4 waves, each 64x64 = 4x4 MFMA tiles).
// LDS pitch 40 (80B) -> 2-way-max bank aliasing on ds_read_b128 (free).
// Epilogues: YENC (y*yW + eb + yb), BIAS, RELU; stores OF32 and/or OB16.
// M%128==0, N%128==0, K%32==0 required.
// ---------------------------------------------------------------------------
template <bool YENC, bool BIAS, bool RELU, bool OF32, bool OB16>
__global__ __launch_bounds__(256)
void gemm_bf16(const unsigned short* __restrict__ A,
               const unsigned short* __restrict__ Bt,
               float* __restrict__ C32, unsigned short* __restrict__ C16,
               const float* __restrict__ bias, const float* __restrict__ yb2,
               const float* __restrict__ yvec, const float* __restrict__ yW,
               int M, int N, int K) {
  __shared__ unsigned short As[128][40];
  __shared__ unsigned short Bs[128][40];
  const int tid = threadIdx.x;
  const int wave = tid >> 6, lane = tid & 63;
  const int q = lane >> 4, c = lane & 15;
  const int wm = wave >> 1, wn = wave & 1;
  const int m0 = blockIdx.y * 128, n0 = blockIdx.x * 128;
  const int sr = tid >> 1;            // staging row 0..127
  const int so = (tid & 1) * 16;      // staging elem offset 0 / 16

  f32x4 acc[4][4];
#pragma unroll
  for (int i = 0; i < 4; ++i)
#pragma unroll
    for (int j = 0; j < 4; ++j) acc[i][j] = (f32x4){0.f, 0.f, 0.f, 0.f};

  for (int k0 = 0; k0 < K; k0 += 32) {
    const uint4* ga = (const uint4*)(A + (size_t)(m0 + sr) * K + k0 + so);
    const uint4 a0 = ga[0], a1 = ga[1];
    const uint4* gb = (const uint4*)(Bt + (size_t)(n0 + sr) * K + k0 + so);
    const uint4 b0 = gb[0], b1 = gb[1];
    __syncthreads();  // previous iteration's reads complete
    *(uint4*)&As[sr][so] = a0; *(uint4*)&As[sr][so + 8] = a1;
    *(uint4*)&Bs[sr][so] = b0; *(uint4*)&Bs[sr][so + 8] = b1;
    __syncthreads();
    s16x8 af[4], bf[4];
#pragma unroll
    for (int mi = 0; mi < 4; ++mi)
      af[mi] = *(const s16x8*)&As[wm * 64 + mi * 16 + c][q * 8];
#pragma unroll
    for (int ni = 0; ni < 4; ++ni)
      bf[ni] = *(const s16x8*)&Bs[wn * 64 + ni * 16 + c][q * 8];
#pragma unroll
    for (int mi = 0; mi < 4; ++mi)
#pragma unroll
      for (int ni = 0; ni < 4; ++ni)
        acc[mi][ni] = __builtin_amdgcn_mfma_f32_16x16x32_bf16(
            af[mi], bf[ni], acc[mi][ni], 0, 0, 0);
  }

  // Epilogue.  C/D layout: col = c (lane&15), row = q*4 + reg.
  float bb[4], yw[4];
#pragma unroll
  for (int ni = 0; ni < 4; ++ni) {
    const int n = n0 + wn * 64 + ni * 16 + c;
    float t = 0.f;
    if (BIAS) t = bias[n];
    if (YENC) t = bias[n] + yb2[n];
    bb[ni] = t;
    yw[ni] = YENC ? yW[n] : 0.f;
  }
#pragma unroll
  for (int mi = 0; mi < 4; ++mi) {
#pragma unroll
    for (int r = 0; r < 4; ++r) {
      const int m = m0 + wm * 64 + mi * 16 + q * 4 + r;
      const float yv = YENC ? yvec[m] : 0.f;
#pragma unroll
      for (int ni = 0; ni < 4; ++ni) {
        const int n = n0 + wn * 64 + ni * 16 + c;
        float val = acc[mi][ni][r] + bb[ni];
        if (YENC) val = fmaf(yv, yw[ni], val);
        if (RELU) val = fmaxf(val, 0.f);
        if (OF32) C32[(size_t)m * N + n] = val;
        if (OB16) C16[(size_t)m * N + n] = f2b(val);
      }
    }
  }
}

// ---------------------------------------------------------------------------
// V transpose: qkv[(s*16+b)*1536 + 1024 + h*64 + d] -> vt[((b*8+h)*64+d)*1024+s]
// grid (16 s-chunks, 8 h, 16 b), 256 threads.
// ---------------------------------------------------------------------------
__global__ __launch_bounds__(256)
void vtrans(const unsigned short* __restrict__ qkv, unsigned short* __restrict__ vt) {
  __shared__ unsigned short t[64][72];
  const int s0 = blockIdx.x * 64;
  const int h = blockIdx.y, b = blockIdx.z;
  const int tid = threadIdx.x;
  const int r = tid >> 2, o = (tid & 3) * 16;
  const unsigned short* g =
      qkv + ((size_t)(s0 + r) * BB + b) * 1536 + 1024 + h * 64 + o;
  unsigned short tmp[16];
  *(uint4*)tmp = *(const uint4*)g;
  *(uint4*)(tmp + 8) = *(const uint4*)(g + 8);
#pragma unroll
  for (int i = 0; i < 16; ++i) t[o + i][r] = tmp[i];
  __syncthreads();
  unsigned short* out =
      vt + ((size_t)(b * NHH + h) * 64 + r) * 1024 + s0 + o;
  *(uint4*)out = *(const uint4*)&t[r][o];
  *(uint4*)(out + 8) = *(const uint4*)&t[r][o + 8];
}

// ---------------------------------------------------------------------------
// Flash attention, bf16 MFMA.  Block = (64 q-rows, h, b); 4 waves x 16 rows.
// S-tiles of 64; K tile [s][d], Vt tile [d][s] in LDS (pitch 72 = 2-way max);
// online softmax in registers; P -> LDS -> A-frag (m120 pattern).
// ---------------------------------------------------------------------------
__global__ __launch_bounds__(256)
void attn_mfma(const unsigned short* __restrict__ qkv,
               const unsigned short* __restrict__ vt,
               unsigned short* __restrict__ aob) {
  __shared__ unsigned short Qs[64][72];
  __shared__ unsigned short Ks[64][72];
  __shared__ unsigned short Vts[64][72];
  __shared__ unsigned short Pls[4][16][72];
  const int tid = threadIdx.x;
  const int w = tid >> 6, lane = tid & 63;
  const int q = lane >> 4, c = lane & 15;
  const int t0 = blockIdx.x * 64;
  const int h = blockIdx.y, b = blockIdx.z;
  const int bh = b * NHH + h;
  const int sr = tid >> 2, so = (tid & 3) * 16;

  // stage Q once: rows t0..t0+63, cols h*64..+63
  {
    const unsigned short* g =
        qkv + ((size_t)(t0 + sr) * BB + b) * 1536 + h * 64 + so;
    *(uint4*)&Qs[sr][so] = *(const uint4*)g;
    *(uint4*)&Qs[sr][so + 8] = *(const uint4*)(g + 8);
  }
  __syncthreads();
  s16x8 aq[2];
  aq[0] = *(const s16x8*)&Qs[w * 16 + c][q * 8];
  aq[1] = *(const s16x8*)&Qs[w * 16 + c][32 + q * 8];

  float m_s[4], l_s[4];
  f32x4 oacc[4];
#pragma unroll
  for (int r = 0; r < 4; ++r) { m_s[r] = -3.0e38f; l_s[r] = 0.f; }
#pragma unroll
  for (int dt = 0; dt < 4; ++dt) oacc[dt] = (f32x4){0.f, 0.f, 0.f, 0.f};

  for (int s0 = 0; s0 < SEP; s0 += 64) {
    // stage K tile [s][d] and Vt tile [d][s]
    {
      const unsigned short* gk =
          qkv + ((size_t)(s0 + sr) * BB + b) * 1536 + 512 + h * 64 + so;
      uint4 k0v = *(const uint4*)gk, k1v = *(const uint4*)(gk + 8);
      const unsigned short* gv = vt + ((size_t)bh * 64 + sr) * 1024 + s0 + so;
      uint4 v0v = *(const uint4*)gv, v1v = *(const uint4*)(gv + 8);
      *(uint4*)&Ks[sr][so] = k0v; *(uint4*)&Ks[sr][so + 8] = k1v;
      *(uint4*)&Vts[sr][so] = v0v; *(uint4*)&Vts[sr][so + 8] = v1v;
    }
    __syncthreads();
    // S = Q K^T * 0.125 for this wave's 16 rows x 64 cols
    f32x4 sacc[4];
#pragma unroll
    for (int ch = 0; ch < 4; ++ch) sacc[ch] = (f32x4){0.f, 0.f, 0.f, 0.f};
#pragma unroll
    for (int ch = 0; ch < 4; ++ch) {
#pragma unroll
      for (int kh = 0; kh < 2; ++kh) {
        s16x8 bk = *(const s16x8*)&Ks[ch * 16 + c][kh * 32 + q * 8];
        sacc[ch] = __builtin_amdgcn_mfma_f32_16x16x32_bf16(
            aq[kh], bk, sacc[ch], 0, 0, 0);
      }
    }
    // online softmax (rows q*4+r held by this lane, cols c of each chunk)
    float rmax[4];
#pragma unroll
    for (int r = 0; r < 4; ++r) {
      float mx = -3.0e38f;
#pragma unroll
      for (int ch = 0; ch < 4; ++ch) mx = fmaxf(mx, sacc[ch][r] * 0.125f);
      rmax[r] = mx;
    }
#pragma unroll
    for (int mask = 1; mask < 16; mask <<= 1)
#pragma unroll
      for (int r = 0; r < 4; ++r)
        rmax[r] = fmaxf(rmax[r], __shfl_xor(rmax[r], mask));
    float alpha[4], rsum[4];
    float p[4][4];
#pragma unroll
    for (int r = 0; r < 4; ++r) {
      const float mnew = fmaxf(m_s[r], rmax[r]);
      alpha[r] = __expf(m_s[r] - mnew);
      float sum = 0.f;
#pragma unroll
      for (int ch = 0; ch < 4; ++ch) {
        const float pv = __expf(sacc[ch][r] * 0.125f - mnew);
        p[ch][r] = pv;
        sum += pv;
      }
      rsum[r] = sum;
      m_s[r] = mnew;
    }
#pragma unroll
    for (int mask = 1; mask < 16; mask <<= 1)
#pragma unroll
      for (int r = 0; r < 4; ++r) rsum[r] += __shfl_xor(rsum[r], mask);
#pragma unroll
    for (int r = 0; r < 4; ++r) l_s[r] = l_s[r] * alpha[r] + rsum[r];
#pragma unroll
    for (int dt = 0; dt < 4; ++dt)
#pragma unroll
      for (int r = 0; r < 4; ++r) oacc[dt][r] *= alpha[r];
    // write P (bf16) to this wave's LDS strip
#pragma unroll
    for (int ch = 0; ch < 4; ++ch)
#pragma unroll
      for (int r = 0; r < 4; ++r)
        Pls[w][q * 4 + r][ch * 16 + c] = f2b(p[ch][r]);
    __syncthreads();
    // O += P @ V  (A = P[t][s], B = V[s][d] via Vt rows)
#pragma unroll
    for (int kh = 0; kh < 2; ++kh) {
      s16x8 ap = *(const s16x8*)&Pls[w][c][kh * 32 + q * 8];
#pragma unroll
      for (int dt = 0; dt < 4; ++dt) {
        s16x8 bv = *(const s16x8*)&Vts[dt * 16 + c][kh * 32 + q * 8];
        oacc[dt] = __builtin_amdgcn_mfma_f32_16x16x32_bf16(
            ap, bv, oacc[dt], 0, 0, 0);
      }
    }
    __syncthreads();
  }
  // normalize + store bf16: row m = t0 + w*16 + q*4 + r, col e = h*64+dt*16+c
  float inv[4];
#pragma unroll
  for (int r = 0; r < 4; ++r) inv[r] = 1.f / l_s[r];
#pragma unroll
  for (int dt = 0; dt < 4; ++dt) {
#pragma unroll
    for (int r = 0; r < 4; ++r) {
      const int m = t0 + w * 16 + q * 4 + r;
      aob[((size_t)m * BB + b) * EE + h * 64 + dt * 16 + c] =
          f2b(oacc[dt][r] * inv[r]);
    }
  }
}

// ---------------------------------------------------------------------------
// LayerNorm: o = LN(a + r) * g + be.  Optionally also emit bf16 copy.
// ---------------------------------------------------------------------------
template <bool B16>
__global__ __launch_bounds__(256)
void ln_k(const float* __restrict__ a, const float* __restrict__ r_,
          const float* __restrict__ g, const float* __restrict__ be,
          float* __restrict__ o32, unsigned short* __restrict__ o16) {
  __shared__ float ss[4], sqs[4];
  const int row = blockIdx.x;
  const int tid = threadIdx.x;
  const size_t base = (size_t)row * EE;
  const float x0 = a[base + tid] + r_[base + tid];
  const float x1 = a[base + tid + 256] + r_[base + tid + 256];
  float s = x0 + x1;
  float sq = x0 * x0 + x1 * x1;
#pragma unroll
  for (int off = 32; off >= 1; off >>= 1) {
    s += __shfl_xor(s, off);
    sq += __shfl_xor(sq, off);
  }
  const int wid = tid >> 6;
  if ((tid & 63) == 0) { ss[wid] = s; sqs[wid] = sq; }
  __syncthreads();
  s = ss[0] + ss[1] + ss[2] + ss[3];
  sq = sqs[0] + sqs[1] + sqs[2] + sqs[3];
  const float mean = s * (1.f / 512.f);
  const float var = sq * (1.f / 512.f) - mean * mean;
  const float rstd = rsqrtf(fmaxf(var, 0.f) + 1e-5f);
  const float v0 = (x0 - mean) * rstd * g[tid] + be[tid];
  const float v1 = (x1 - mean) * rstd * g[tid + 256] + be[tid + 256];
  o32[base + tid] = v0;
  o32[base + tid + 256] = v1;
  if (B16) {
    o16[base + tid] = f2b(v0);
    o16[base + tid + 256] = f2b(v1);
  }
}

// pooled[b*E+e] = mean over t of out[t,b,e]
__global__ __launch_bounds__(256)
void pool_f32(const float* __restrict__ outb, float* __restrict__ pooled) {
  const int i = blockIdx.x * 256 + threadIdx.x;  // < B*E
  float s = 0.f;
  for (int t = 0; t < SEP; ++t) s += outb[(size_t)t * (BB * EE) + i];
  pooled[i] = s * (1.f / (float)SEP);
}

// dh[b,n] = relu(pooled[b,:] @ dec_W[:,n] + dec_b[n])
__global__ __launch_bounds__(256)
void dec_f32(const float* __restrict__ pooled, const float* __restrict__ dW,
             const float* __restrict__ db, float* __restrict__ dh) {
  const int n = blockIdx.x * 256 + threadIdx.x;  // < DEC
  const int b = blockIdx.y;
  const float* pp = pooled + b * EE;
  float acc = db[n];
  for (int k = 0; k < EE; ++k) acc = fmaf(pp[k], dW[(size_t)k * DECN + n], acc);
  dh[b * DECN + n] = fmaxf(acc, 0.f);
}

// C[b, n] = dh[b, :] @ W[:, n]   (K = DEC = 1024, all 16 b per thread)
__global__ __launch_bounds__(256)
void headgemm(const float* __restrict__ dh, const float* __restrict__ W,
              float* __restrict__ C, int N) {
  __shared__ float ds[16][128];
  const int n = blockIdx.x * 256 + threadIdx.x;
  float acc[16];
#pragma unroll
  for (int i = 0; i < 16; ++i) acc[i] = 0.f;
  for (int k0 = 0; k0 < DECN; k0 += 128) {
    __syncthreads();
    for (int i = threadIdx.x; i < 2048; i += 256)
      ds[i >> 7][i & 127] = dh[(size_t)(i >> 7) * DECN + k0 + (i & 127)];
    __syncthreads();
    if (n < N) {
      for (int kk = 0; kk < 128; ++kk) {
        const float w = W[(size_t)(k0 + kk) * N + n];
#pragma unroll
        for (int bb = 0; bb < 16; ++bb) acc[bb] = fmaf(ds[bb][kk], w, acc[bb]);
      }
    }
  }
  if (n < N) {
#pragma unroll
    for (int bb = 0; bb < 16; ++bb) C[(size_t)bb * N + n] = acc[bb];
  }
}

// h1[e,b,h] = relu(nan2num(x[sep+e,b,:]) @ w1[b,:,h] + b1[b,h])
__global__ __launch_bounds__(256)
void eval1_kernel(const float* __restrict__ x, const float* __restrict__ w1,
                  const float* __restrict__ b1, float* __restrict__ h1) {
  __shared__ float xs[8][100];
  const int b = blockIdx.z;
  const int e0 = blockIdx.y << 3;
  const int hcol = blockIdx.x * 256 + threadIdx.x;
  for (int i = threadIdx.x; i < 800; i += 256) {
    const int ee = i / 100, f = i - ee * 100;
    xs[ee][f] = nan2num(x[((size_t)(SEP + e0 + ee) * BB + b) * FIN + f]);
  }
  __syncthreads();
  float acc[8];
#pragma unroll
  for (int i = 0; i < 8; ++i) acc[i] = 0.f;
  for (int f = 0; f < FIN; ++f) {
    const float w = w1[(size_t)b * (FIN * HHN) + (size_t)f * HHN + hcol];
#pragma unroll
    for (int ee = 0; ee < 8; ++ee) acc[ee] = fmaf(xs[ee][f], w, acc[ee]);
  }
  const float bias = b1[b * HHN + hcol];
#pragma unroll
  for (int ee = 0; ee < 8; ++ee)
    h1[((size_t)(e0 + ee) * BB + b) * HHN + hcol] = fmaxf(acc[ee] + bias, 0.f);
}

// out[e,b,o] = h1[e,b,:] @ w2[b,:,o] + b2[b,o]
__global__ __launch_bounds__(256)
void eval2_kernel(const float* __restrict__ h1, const float* __restrict__ w2,
                  const float* __restrict__ b2, float* __restrict__ outp) {
  const int idx = blockIdx.x * 256 + threadIdx.x;  // < EVALN*BB*NOUT
  const int o = idx % NOUTN;
  const int eb = idx / NOUTN;
  const int b = eb & (BB - 1);
  const float* hp = h1 + (size_t)eb * HHN;
  const float* wp = w2 + (size_t)b * (HHN * NOUTN) + o;
  float acc = b2[b * NOUTN + o];
  for (int k = 0; k < HHN; ++k) acc = fmaf(hp[k], wp[(size_t)k * NOUTN], acc);
  outp[idx] = acc;
}

// ---------------------------------------------------------------------------
extern "C" void kernel_launch(void* const* d_in, const int* in_sizes, int n_in,
                              void* d_out, int out_size, void* d_ws, size_t ws_size,
                              hipStream_t stream) {
  const float* x      = (const float*)d_in[0];
  const float* y      = (const float*)d_in[1];
  const float* enc_W  = (const float*)d_in[2];
  const float* enc_b  = (const float*)d_in[3];
  const float* yenc_W = (const float*)d_in[4];
  const float* yenc_b = (const float*)d_in[5];
  const float* Wq     = (const float*)d_in[6];
  const float* Wk     = (const float*)d_in[7];
  const float* Wv     = (const float*)d_in[8];
  const float* Wo     = (const float*)d_in[9];
  const float* ln1_g  = (const float*)d_in[10];
  const float* ln1_b  = (const float*)d_in[11];
  const float* ln2_g  = (const float*)d_in[12];
  const float* ln2_b  = (const float*)d_in[13];
  const float* ffn_W1 = (const float*)d_in[14];
  const float* ffn_b1 = (const float*)d_in[15];
  const float* ffn_W2 = (const float*)d_in[16];
  const float* ffn_b2 = (const float*)d_in[17];
  const float* dec_W  = (const float*)d_in[18];
  const float* dec_b  = (const float*)d_in[19];
  const float* hw1    = (const float*)d_in[20];
  const float* hb1    = (const float*)d_in[21];
  const float* hw2    = (const float*)d_in[22];
  const float* hb2    = (const float*)d_in[23];

  char* ws = (char*)d_ws;
  // Byte-offset arena (lifetimes disjoint where overlapped):
  unsigned short* ff1b  = (unsigned short*)(ws + 0 * MB);    // 64MB (step 8)
  unsigned short* xb    = (unsigned short*)(ws + 0 * MB);    //  4MB (steps 1-2)
  unsigned short* txb   = (unsigned short*)(ws + 16 * MB);   // 16MB (2-3)
  unsigned short* vt    = (unsigned short*)(ws + 32 * MB);   // 16MB (4-5)
  unsigned short* aob   = (unsigned short*)(ws + 48 * MB);   // 16MB (5-6)
  unsigned short* qkvb  = (unsigned short*)(ws + 64 * MB);   // 48MB (3-5)
  float*          z32   = (float*)(ws + 64 * MB);            // 32MB (7-10)
  unsigned short* zb    = (unsigned short*)(ws + 96 * MB);   // 16MB (7-8)
  float*          tx32  = (float*)(ws + 112 * MB);           // 32MB (2-7)
  float*          ff2   = (float*)(ws + 112 * MB);           // 32MB (9-10)
  float*          aop   = (float*)(ws + 144 * MB);           // 32MB (6-7)
  float*          outb  = (float*)(ws + 144 * MB);           // 32MB (10-11)
  float*          h1    = (float*)(ws + 144 * MB);           // 32MB (eval)
  size_t wo_ = 176 * (size_t)MB;
  unsigned short* WencT = (unsigned short*)(ws + wo_); wo_ += (size_t)EE * FINP * 2;
  unsigned short* WqkvT = (unsigned short*)(ws + wo_); wo_ += (size_t)3 * EE * EE * 2;
  unsigned short* WoT   = (unsigned short*)(ws + wo_); wo_ += (size_t)EE * EE * 2;
  unsigned short* W1T   = (unsigned short*)(ws + wo_); wo_ += (size_t)FFNN * EE * 2;
  unsigned short* W2T   = (unsigned short*)(ws + wo_); wo_ += (size_t)EE * FFNN * 2;
  float* pooled = (float*)(ws + wo_); wo_ += (size_t)BB * EE * 4;
  float* dh     = (float*)(ws + wo_); wo_ += (size_t)BB * DECN * 4;
  float* w1g    = (float*)(ws + wo_); wo_ += (size_t)BB * FIN * HHN * 4;
  float* b1g    = (float*)(ws + wo_); wo_ += (size_t)BB * HHN * 4;
  float* w2g    = (float*)(ws + wo_); wo_ += (size_t)BB * HHN * NOUTN * 4;
  float* b2g    = (float*)(ws + wo_);
  float* outp = (float*)d_out;

  // 0) weight prep (bf16, transposed [N][K])
  transcast<<<dim3(EE / 32, FINP / 32), dim3(32, 8), 0, stream>>>(enc_W, WencT, FIN, EE, FINP);
  transcast<<<dim3(EE / 32, EE / 32), dim3(32, 8), 0, stream>>>(Wq, WqkvT, EE, EE, EE);
  transcast<<<dim3(EE / 32, EE / 32), dim3(32, 8), 0, stream>>>(Wk, WqkvT + (size_t)EE * EE, EE, EE, EE);
  transcast<<<dim3(EE / 32, EE / 32), dim3(32, 8), 0, stream>>>(Wv, WqkvT + (size_t)2 * EE * EE, EE, EE, EE);
  transcast<<<dim3(EE / 32, EE / 32), dim3(32, 8), 0, stream>>>(Wo, WoT, EE, EE, EE);
  transcast<<<dim3(FFNN / 32, EE / 32), dim3(32, 8), 0, stream>>>(ffn_W1, W1T, EE, FFNN, EE);
  transcast<<<dim3(EE / 32, FFNN / 32), dim3(32, 8), 0, stream>>>(ffn_W2, W2T, FFNN, EE, FFNN);
  castx_kernel<<<(TBR * FINP) / 256, 256, 0, stream>>>(x, xb);

  // 1) encoder: tx = xb @ WencT^T + y*yW + yb + eb   -> tx32 (f32) + txb (bf16)
  gemm_bf16<true, false, false, true, true><<<dim3(EE / 128, TBR / 128), 256, 0, stream>>>(
      xb, WencT, tx32, txb, enc_b, yenc_b, y, yenc_W, TBR, EE, FINP);
  // 2) fused QKV (N=1536) -> bf16
  gemm_bf16<false, false, false, false, true><<<dim3(1536 / 128, TBR / 128), 256, 0, stream>>>(
      txb, WqkvT, nullptr, qkvb, nullptr, nullptr, nullptr, nullptr, TBR, 1536, EE);
  // 3) V transpose for PV B-operand
  vtrans<<<dim3(SEP / 64, NHH, BB), 256, 0, stream>>>(qkvb, vt);
  // 4) flash attention -> aob bf16
  attn_mfma<<<dim3(SEP / 64, NHH, BB), 256, 0, stream>>>(qkvb, vt, aob);
  // 5) Wo projection -> aop f32
  gemm_bf16<false, false, false, true, false><<<dim3(EE / 128, TBR / 128), 256, 0, stream>>>(
      aob, WoT, aop, nullptr, nullptr, nullptr, nullptr, nullptr, TBR, EE, EE);
  // 6) LN1 -> z32 + zb
  ln_k<true><<<TBR, 256, 0, stream>>>(tx32, aop, ln1_g, ln1_b, z32, zb);
  // 7) FFN1 (bias+relu) -> ff1b bf16
  gemm_bf16<false, true, true, false, true><<<dim3(FFNN / 128, TBR / 128), 256, 0, stream>>>(
      zb, W1T, nullptr, ff1b, ffn_b1, nullptr, nullptr, nullptr, TBR, FFNN, EE);
  // 8) FFN2 (bias) -> ff2 f32
  gemm_bf16<false, true, false, true, false><<<dim3(EE / 128, TBR / 128), 256, 0, stream>>>(
      ff1b, W2T, ff2, nullptr, ffn_b2, nullptr, nullptr, nullptr, TBR, EE, FFNN);
  // 9) LN2 -> outb
  ln_k<false><<<TBR, 256, 0, stream>>>(z32, ff2, ln2_g, ln2_b, outb, nullptr);
  // 10) decoder + per-batch head weights (fp32, exact)
  pool_f32<<<(BB * EE) / 256, 256, 0, stream>>>(outb, pooled);
  dec_f32<<<dim3(DECN / 256, BB), 256, 0, stream>>>(pooled, dec_W, dec_b, dh);
  headgemm<<<(FIN * HHN) / 256, 256, 0, stream>>>(dh, hw1, w1g, FIN * HHN);
  headgemm<<<HHN / 256, 256, 0, stream>>>(dh, hb1, b1g, HHN);
  headgemm<<<(HHN * NOUTN + 255) / 256, 256, 0, stream>>>(dh, hw2, w2g, HHN * NOUTN);
  headgemm<<<1, 256, 0, stream>>>(dh, hb2, b2g, NOUTN);
  // 11) generated per-batch MLP on eval tokens
  eval1_kernel<<<dim3(HHN / 256, EVALN / 8, BB), 256, 0, stream>>>(x, w1g, b1g, h1);
  eval2_kernel<<<(EVALN * BB * NOUTN) / 256, 256, 0, stream>>>(h1, w2g, b2g, outp);
}

// Round 3
// 879.290 us; speedup vs baseline: 5.8226x; 2.0113x over previous
//
#include <hip/hip_runtime.h>
#include <math.h>

// Problem constants: S=2048, B=16, F=100, E=512, NH=8, DH=64, FF=2048,
// DEC=1024, H=512, NOUT=10, sep=1024 (structural).
#define SEP   1024
#define EVALN 1024
#define BB    16
#define FIN   100
#define FINP  128          // F padded to 128 for bf16 GEMM (zeros)
#define EE    512
#define NHH   8
#define DHH   64
#define FFNN  2048
#define DECN  1024
#define HHN   512
#define NOUTN 10
#define TBR   (SEP * BB)   // 16384 token rows
#define MB    (1024u * 1024u)

typedef short  s16x8 __attribute__((ext_vector_type(8)));
typedef float  f32x4 __attribute__((ext_vector_type(4)));

__device__ __forceinline__ unsigned short f2b(float f) {
  union { float f; unsigned int u; } v; v.f = f;
  unsigned int u = v.u;
  return (unsigned short)((u + 0x7fffu + ((u >> 16) & 1u)) >> 16);
}

__device__ __forceinline__ float nan2num(float v) {
  if (isnan(v)) return 0.f;
  if (isinf(v)) return v > 0.f ? 3.4028234663852886e38f : -3.4028234663852886e38f;
  return v;
}

// ---------------------------------------------------------------------------
// Weight transpose+cast: W[K][N] f32 -> Wt[N][Kp] bf16 (zero-padded K..Kp).
// ---------------------------------------------------------------------------
__global__ __launch_bounds__(256)
void transcast(const float* __restrict__ W, unsigned short* __restrict__ Wt,
               int K, int N, int Kp) {
  __shared__ float t[32][33];
  const int n0 = blockIdx.x * 32, k0 = blockIdx.y * 32;
  const int tx = threadIdx.x, ty = threadIdx.y;
#pragma unroll
  for (int r = 0; r < 4; ++r) {
    const int k = k0 + ty + r * 8;
    t[ty + r * 8][tx] = (k < K) ? W[(size_t)k * N + n0 + tx] : 0.f;
  }
  __syncthreads();
#pragma unroll
  for (int r = 0; r < 4; ++r) {
    const int n = n0 + ty + r * 8;
    Wt[(size_t)n * Kp + k0 + tx] = f2b(t[tx][ty + r * 8]);
  }
}

// x[:sep] f32 [16384][100] -> xb bf16 [16384][128] (zero-padded)
__global__ __launch_bounds__(256)
void castx_kernel(const float* __restrict__ x, unsigned short* __restrict__ xb) {
  const int idx = blockIdx.x * 256 + threadIdx.x;
  const int m = idx >> 7, f = idx & 127;
  xb[idx] = (f < FIN) ? f2b(x[(size_t)m * FIN + f]) : (unsigned short)0;
}

// ---------------------------------------------------------------------------
// bf16 MFMA GEMM: C[M,N] = A[M,K](bf16) @ Bt[N,K](bf16)^T  + epilogue.
// ---------------------------------------------------------------------------
template <bool YENC, bool BIAS, bool RELU, bool OF32, bool OB16>
__global__ __launch_bounds__(256)
void gemm_bf16(const unsigned short* __restrict__ A,
               const unsigned short* __restrict__ Bt,
               float* __restrict__ C32, unsigned short* __restrict__ C16,
               const float* __restrict__ bias, const float* __restrict__ yb2,
               const float* __restrict__ yvec, const float* __restrict__ yW,
               int M, int N, int K) {
  __shared__ unsigned short As[128][40];
  __shared__ unsigned short Bs[128][40];
  const int tid = threadIdx.x;
  const int wave = tid >> 6, lane = tid & 63;
  const int q = lane >> 4, c = lane & 15;
  const int wm = wave >> 1, wn = wave & 1;
  const int m0 = blockIdx.y * 128, n0 = blockIdx.x * 128;
  const int sr = tid >> 1;
  const int so = (tid & 1) * 16;

  f32x4 acc[4][4];
#pragma unroll
  for (int i = 0; i < 4; ++i)
#pragma unroll
    for (int j = 0; j < 4; ++j) acc[i][j] = (f32x4){0.f, 0.f, 0.f, 0.f};

  for (int k0 = 0; k0 < K; k0 += 32) {
    const uint4* ga = (const uint4*)(A + (size_t)(m0 + sr) * K + k0 + so);
    const uint4 a0 = ga[0], a1 = ga[1];
    const uint4* gb = (const uint4*)(Bt + (size_t)(n0 + sr) * K + k0 + so);
    const uint4 b0 = gb[0], b1 = gb[1];
    __syncthreads();
    *(uint4*)&As[sr][so] = a0; *(uint4*)&As[sr][so + 8] = a1;
    *(uint4*)&Bs[sr][so] = b0; *(uint4*)&Bs[sr][so + 8] = b1;
    __syncthreads();
    s16x8 af[4], bf[4];
#pragma unroll
    for (int mi = 0; mi < 4; ++mi)
      af[mi] = *(const s16x8*)&As[wm * 64 + mi * 16 + c][q * 8];
#pragma unroll
    for (int ni = 0; ni < 4; ++ni)
      bf[ni] = *(const s16x8*)&Bs[wn * 64 + ni * 16 + c][q * 8];
#pragma unroll
    for (int mi = 0; mi < 4; ++mi)
#pragma unroll
      for (int ni = 0; ni < 4; ++ni)
        acc[mi][ni] = __builtin_amdgcn_mfma_f32_16x16x32_bf16(
            af[mi], bf[ni], acc[mi][ni], 0, 0, 0);
  }

  float bb[4], yw[4];
#pragma unroll
  for (int ni = 0; ni < 4; ++ni) {
    const int n = n0 + wn * 64 + ni * 16 + c;
    float t = 0.f;
    if (BIAS) t = bias[n];
    if (YENC) t = bias[n] + yb2[n];
    bb[ni] = t;
    yw[ni] = YENC ? yW[n] : 0.f;
  }
#pragma unroll
  for (int mi = 0; mi < 4; ++mi) {
#pragma unroll
    for (int r = 0; r < 4; ++r) {
      const int m = m0 + wm * 64 + mi * 16 + q * 4 + r;
      const float yv = YENC ? yvec[m] : 0.f;
#pragma unroll
      for (int ni = 0; ni < 4; ++ni) {
        const int n = n0 + wn * 64 + ni * 16 + c;
        float val = acc[mi][ni][r] + bb[ni];
        if (YENC) val = fmaf(yv, yw[ni], val);
        if (RELU) val = fmaxf(val, 0.f);
        if (OF32) C32[(size_t)m * N + n] = val;
        if (OB16) C16[(size_t)m * N + n] = f2b(val);
      }
    }
  }
}

// ---------------------------------------------------------------------------
// V transpose for PV B-operand.
// ---------------------------------------------------------------------------
__global__ __launch_bounds__(256)
void vtrans(const unsigned short* __restrict__ qkv, unsigned short* __restrict__ vt) {
  __shared__ unsigned short t[64][72];
  const int s0 = blockIdx.x * 64;
  const int h = blockIdx.y, b = blockIdx.z;
  const int tid = threadIdx.x;
  const int r = tid >> 2, o = (tid & 3) * 16;
  const unsigned short* g =
      qkv + ((size_t)(s0 + r) * BB + b) * 1536 + 1024 + h * 64 + o;
  unsigned short tmp[16];
  *(uint4*)tmp = *(const uint4*)g;
  *(uint4*)(tmp + 8) = *(const uint4*)(g + 8);
#pragma unroll
  for (int i = 0; i < 16; ++i) t[o + i][r] = tmp[i];
  __syncthreads();
  unsigned short* out =
      vt + ((size_t)(b * NHH + h) * 64 + r) * 1024 + s0 + o;
  *(uint4*)out = *(const uint4*)&t[r][o];
  *(uint4*)(out + 8) = *(const uint4*)&t[r][o + 8];
}

// ---------------------------------------------------------------------------
// Flash attention, bf16 MFMA (64 q-rows per block, online softmax).
// ---------------------------------------------------------------------------
__global__ __launch_bounds__(256)
void attn_mfma(const unsigned short* __restrict__ qkv,
               const unsigned short* __restrict__ vt,
               unsigned short* __restrict__ aob) {
  __shared__ unsigned short Qs[64][72];
  __shared__ unsigned short Ks[64][72];
  __shared__ unsigned short Vts[64][72];
  __shared__ unsigned short Pls[4][16][72];
  const int tid = threadIdx.x;
  const int w = tid >> 6, lane = tid & 63;
  const int q = lane >> 4, c = lane & 15;
  const int t0 = blockIdx.x * 64;
  const int h = blockIdx.y, b = blockIdx.z;
  const int bh = b * NHH + h;
  const int sr = tid >> 2, so = (tid & 3) * 16;

  {
    const unsigned short* g =
        qkv + ((size_t)(t0 + sr) * BB + b) * 1536 + h * 64 + so;
    *(uint4*)&Qs[sr][so] = *(const uint4*)g;
    *(uint4*)&Qs[sr][so + 8] = *(const uint4*)(g + 8);
  }
  __syncthreads();
  s16x8 aq[2];
  aq[0] = *(const s16x8*)&Qs[w * 16 + c][q * 8];
  aq[1] = *(const s16x8*)&Qs[w * 16 + c][32 + q * 8];

  float m_s[4], l_s[4];
  f32x4 oacc[4];
#pragma unroll
  for (int r = 0; r < 4; ++r) { m_s[r] = -3.0e38f; l_s[r] = 0.f; }
#pragma unroll
  for (int dt = 0; dt < 4; ++dt) oacc[dt] = (f32x4){0.f, 0.f, 0.f, 0.f};

  for (int s0 = 0; s0 < SEP; s0 += 64) {
    {
      const unsigned short* gk =
          qkv + ((size_t)(s0 + sr) * BB + b) * 1536 + 512 + h * 64 + so;
      uint4 k0v = *(const uint4*)gk, k1v = *(const uint4*)(gk + 8);
      const unsigned short* gv = vt + ((size_t)bh * 64 + sr) * 1024 + s0 + so;
      uint4 v0v = *(const uint4*)gv, v1v = *(const uint4*)(gv + 8);
      *(uint4*)&Ks[sr][so] = k0v; *(uint4*)&Ks[sr][so + 8] = k1v;
      *(uint4*)&Vts[sr][so] = v0v; *(uint4*)&Vts[sr][so + 8] = v1v;
    }
    __syncthreads();
    f32x4 sacc[4];
#pragma unroll
    for (int ch = 0; ch < 4; ++ch) sacc[ch] = (f32x4){0.f, 0.f, 0.f, 0.f};
#pragma unroll
    for (int ch = 0; ch < 4; ++ch) {
#pragma unroll
      for (int kh = 0; kh < 2; ++kh) {
        s16x8 bk = *(const s16x8*)&Ks[ch * 16 + c][kh * 32 + q * 8];
        sacc[ch] = __builtin_amdgcn_mfma_f32_16x16x32_bf16(
            aq[kh], bk, sacc[ch], 0, 0, 0);
      }
    }
    float rmax[4];
#pragma unroll
    for (int r = 0; r < 4; ++r) {
      float mx = -3.0e38f;
#pragma unroll
      for (int ch = 0; ch < 4; ++ch) mx = fmaxf(mx, sacc[ch][r] * 0.125f);
      rmax[r] = mx;
    }
#pragma unroll
    for (int mask = 1; mask < 16; mask <<= 1)
#pragma unroll
      for (int r = 0; r < 4; ++r)
        rmax[r] = fmaxf(rmax[r], __shfl_xor(rmax[r], mask));
    float alpha[4], rsum[4];
    float p[4][4];
#pragma unroll
    for (int r = 0; r < 4; ++r) {
      const float mnew = fmaxf(m_s[r], rmax[r]);
      alpha[r] = __expf(m_s[r] - mnew);
      float sum = 0.f;
#pragma unroll
      for (int ch = 0; ch < 4; ++ch) {
        const float pv = __expf(sacc[ch][r] * 0.125f - mnew);
        p[ch][r] = pv;
        sum += pv;
      }
      rsum[r] = sum;
      m_s[r] = mnew;
    }
#pragma unroll
    for (int mask = 1; mask < 16; mask <<= 1)
#pragma unroll
      for (int r = 0; r < 4; ++r) rsum[r] += __shfl_xor(rsum[r], mask);
#pragma unroll
    for (int r = 0; r < 4; ++r) l_s[r] = l_s[r] * alpha[r] + rsum[r];
#pragma unroll
    for (int dt = 0; dt < 4; ++dt)
#pragma unroll
      for (int r = 0; r < 4; ++r) oacc[dt][r] *= alpha[r];
#pragma unroll
    for (int ch = 0; ch < 4; ++ch)
#pragma unroll
      for (int r = 0; r < 4; ++r)
        Pls[w][q * 4 + r][ch * 16 + c] = f2b(p[ch][r]);
    __syncthreads();
#pragma unroll
    for (int kh = 0; kh < 2; ++kh) {
      s16x8 ap = *(const s16x8*)&Pls[w][c][kh * 32 + q * 8];
#pragma unroll
      for (int dt = 0; dt < 4; ++dt) {
        s16x8 bv = *(const s16x8*)&Vts[dt * 16 + c][kh * 32 + q * 8];
        oacc[dt] = __builtin_amdgcn_mfma_f32_16x16x32_bf16(
            ap, bv, oacc[dt], 0, 0, 0);
      }
    }
    __syncthreads();
  }
  float inv[4];
#pragma unroll
  for (int r = 0; r < 4; ++r) inv[r] = 1.f / l_s[r];
#pragma unroll
  for (int dt = 0; dt < 4; ++dt) {
#pragma unroll
    for (int r = 0; r < 4; ++r) {
      const int m = t0 + w * 16 + q * 4 + r;
      aob[((size_t)m * BB + b) * EE + h * 64 + dt * 16 + c] =
          f2b(oacc[dt][r] * inv[r]);
    }
  }
}

// ---------------------------------------------------------------------------
// LayerNorm: o = LN(a + r) * g + be.  Optionally also emit bf16 copy.
// ---------------------------------------------------------------------------
template <bool B16>
__global__ __launch_bounds__(256)
void ln_k(const float* __restrict__ a, const float* __restrict__ r_,
          const float* __restrict__ g, const float* __restrict__ be,
          float* __restrict__ o32, unsigned short* __restrict__ o16) {
  __shared__ float ss[4], sqs[4];
  const int row = blockIdx.x;
  const int tid = threadIdx.x;
  const size_t base = (size_t)row * EE;
  const float x0 = a[base + tid] + r_[base + tid];
  const float x1 = a[base + tid + 256] + r_[base + tid + 256];
  float s = x0 + x1;
  float sq = x0 * x0 + x1 * x1;
#pragma unroll
  for (int off = 32; off >= 1; off >>= 1) {
    s += __shfl_xor(s, off);
    sq += __shfl_xor(sq, off);
  }
  const int wid = tid >> 6;
  if ((tid & 63) == 0) { ss[wid] = s; sqs[wid] = sq; }
  __syncthreads();
  s = ss[0] + ss[1] + ss[2] + ss[3];
  sq = sqs[0] + sqs[1] + sqs[2] + sqs[3];
  const float mean = s * (1.f / 512.f);
  const float var = sq * (1.f / 512.f) - mean * mean;
  const float rstd = rsqrtf(fmaxf(var, 0.f) + 1e-5f);
  const float v0 = (x0 - mean) * rstd * g[tid] + be[tid];
  const float v1 = (x1 - mean) * rstd * g[tid + 256] + be[tid + 256];
  o32[base + tid] = v0;
  o32[base + tid + 256] = v1;
  if (B16) {
    o16[base + tid] = f2b(v0);
    o16[base + tid + 256] = f2b(v1);
  }
}

// ---------------------------------------------------------------------------
// Decoder tail — latency-bound fixes: K-split partials + reduce everywhere.
// ---------------------------------------------------------------------------
// pool stage 1: pp[ts][i] = sum over 64 t of outb[ts*64+t][i];  grid (32, 16)
__global__ __launch_bounds__(256)
void pool1(const float* __restrict__ outb, float* __restrict__ pp) {
  const int i = blockIdx.x * 256 + threadIdx.x;      // < 8192
  const int ts = blockIdx.y;
  const float* p = outb + (size_t)ts * 64 * (BB * EE) + i;
  float s0 = 0.f, s1 = 0.f, s2 = 0.f, s3 = 0.f;
  for (int t = 0; t < 64; t += 4) {
    s0 += p[(size_t)(t + 0) * (BB * EE)];
    s1 += p[(size_t)(t + 1) * (BB * EE)];
    s2 += p[(size_t)(t + 2) * (BB * EE)];
    s3 += p[(size_t)(t + 3) * (BB * EE)];
  }
  pp[ts * (BB * EE) + i] = (s0 + s1) + (s2 + s3);
}

// pool stage 2: pooled[i] = sum over 16 ts / 1024;  grid (32)
__global__ __launch_bounds__(256)
void pool2(const float* __restrict__ pp, float* __restrict__ pooled) {
  const int i = blockIdx.x * 256 + threadIdx.x;
  float s = 0.f;
#pragma unroll
  for (int ts = 0; ts < 16; ++ts) s += pp[ts * (BB * EE) + i];
  pooled[i] = s * (1.f / (float)SEP);
}

// dec stage 1: pd[(ks*16+b)][n] = pooled[b][ks*128:+128] @ dW-slice; grid (4,16)
__global__ __launch_bounds__(256)
void dec1(const float* __restrict__ pooled, const float* __restrict__ dW,
          float* __restrict__ pd) {
  __shared__ float ps[128];
  const int ks = blockIdx.x, b = blockIdx.y;
  const int tid = threadIdx.x;
  if (tid < 128) ps[tid] = pooled[b * EE + ks * 128 + tid];
  __syncthreads();
  const int n = tid * 4;
  float4 acc = {0.f, 0.f, 0.f, 0.f};
  for (int kk = 0; kk < 128; kk += 4) {
    const float4 p4 = *(const float4*)&ps[kk];
#pragma unroll
    for (int i = 0; i < 4; ++i) {
      const float4 w4 = *(const float4*)&dW[(size_t)(ks * 128 + kk + i) * DECN + n];
      const float pv = (i == 0) ? p4.x : (i == 1) ? p4.y : (i == 2) ? p4.z : p4.w;
      acc.x = fmaf(pv, w4.x, acc.x); acc.y = fmaf(pv, w4.y, acc.y);
      acc.z = fmaf(pv, w4.z, acc.z); acc.w = fmaf(pv, w4.w, acc.w);
    }
  }
  *(float4*)&pd[(size_t)(ks * BB + b) * DECN + n] = acc;
}

// dec stage 2: dh[b][n] = relu(sum_ks pd + db[n]);  grid (64)
__global__ __launch_bounds__(256)
void dec2(const float* __restrict__ pd, const float* __restrict__ db,
          float* __restrict__ dh) {
  const int idx = blockIdx.x * 256 + threadIdx.x;    // < 16384
  const int b = idx >> 10, n = idx & 1023;
  float s = db[n];
#pragma unroll
  for (int ks = 0; ks < 4; ++ks) s += pd[(size_t)(ks * BB + b) * DECN + n];
  dh[idx] = fmaxf(s, 0.f);
}

// head GEMM K-split: part[slice][b*N+n] = dh[b][k-slice] @ W[k-slice][n]
// grid (ceil(N/1024), nslices); KL = K per slice.  dh is [16][1024] f32.
template <int KL>
__global__ __launch_bounds__(256)
void hgemm_split(const float* __restrict__ dh, const float* __restrict__ W,
                 float* __restrict__ part, int N) {
  __shared__ float dhs[16][KL];
  const int tid = threadIdx.x;
  const int n0 = blockIdx.x * 1024;
  const int k0 = blockIdx.y * KL;
  for (int i = tid; i < 16 * (KL / 4); i += 256) {
    const int b = i / (KL / 4), kq = i % (KL / 4);
    *(float4*)&dhs[b][kq * 4] = *(const float4*)&dh[b * DECN + k0 + kq * 4];
  }
  __syncthreads();
  float* pb = part + (size_t)blockIdx.y * 16 * N;
  if ((N & 3) == 0) {
    const int n = n0 + tid * 4;
    if (n + 3 < N) {
      float4 acc[16];
#pragma unroll
      for (int b = 0; b < 16; ++b) acc[b] = (float4){0.f, 0.f, 0.f, 0.f};
      for (int kk = 0; kk < KL; kk += 4) {
        float4 w4[4];
#pragma unroll
        for (int i = 0; i < 4; ++i)
          w4[i] = *(const float4*)&W[(size_t)(k0 + kk + i) * N + n];
#pragma unroll
        for (int b = 0; b < 16; ++b) {
          const float4 d4 = *(const float4*)&dhs[b][kk];
          acc[b].x = fmaf(d4.x, w4[0].x, acc[b].x);
          acc[b].y = fmaf(d4.x, w4[0].y, acc[b].y);
          acc[b].z = fmaf(d4.x, w4[0].z, acc[b].z);
          acc[b].w = fmaf(d4.x, w4[0].w, acc[b].w);
          acc[b].x = fmaf(d4.y, w4[1].x, acc[b].x);
          acc[b].y = fmaf(d4.y, w4[1].y, acc[b].y);
          acc[b].z = fmaf(d4.y, w4[1].z, acc[b].z);
          acc[b].w = fmaf(d4.y, w4[1].w, acc[b].w);
          acc[b].x = fmaf(d4.z, w4[2].x, acc[b].x);
          acc[b].y = fmaf(d4.z, w4[2].y, acc[b].y);
          acc[b].z = fmaf(d4.z, w4[2].z, acc[b].z);
          acc[b].w = fmaf(d4.z, w4[2].w, acc[b].w);
          acc[b].x = fmaf(d4.w, w4[3].x, acc[b].x);
          acc[b].y = fmaf(d4.w, w4[3].y, acc[b].y);
          acc[b].z = fmaf(d4.w, w4[3].z, acc[b].z);
          acc[b].w = fmaf(d4.w, w4[3].w, acc[b].w);
        }
      }
#pragma unroll
      for (int b = 0; b < 16; ++b) *(float4*)&pb[(size_t)b * N + n] = acc[b];
    }
  } else {
    const int n = n0 + tid;
    if (n < N) {
      float acc[16];
#pragma unroll
      for (int b = 0; b < 16; ++b) acc[b] = 0.f;
      for (int kk = 0; kk < KL; ++kk) {
        const float w = W[(size_t)(k0 + kk) * N + n];
#pragma unroll
        for (int b = 0; b < 16; ++b) acc[b] = fmaf(dhs[b][kk], w, acc[b]);
      }
#pragma unroll
      for (int b = 0; b < 16; ++b) pb[(size_t)b * N + n] = acc[b];
    }
  }
}

// reduce S partial slices of `total` (=16*N) elements each
__global__ __launch_bounds__(256)
void hg_reduce(const float* __restrict__ part, float* __restrict__ out,
               int total, int S) {
  const int i4 = (blockIdx.x * 256 + threadIdx.x) * 4;
  if (i4 >= total) return;
  float4 s = *(const float4*)&part[i4];
  for (int p = 1; p < S; ++p) {
    const float4 v = *(const float4*)&part[(size_t)p * total + i4];
    s.x += v.x; s.y += v.y; s.z += v.z; s.w += v.w;
  }
  *(float4*)&out[i4] = s;
}

// h1[e,b,h] = relu(nan2num(x[sep+e,b,:]) @ w1[b,:,h] + b1[b,h])
__global__ __launch_bounds__(256)
void eval1_kernel(const float* __restrict__ x, const float* __restrict__ w1,
                  const float* __restrict__ b1, float* __restrict__ h1) {
  __shared__ float xs[8][100];
  const int b = blockIdx.z;
  const int e0 = blockIdx.y << 3;
  const int hcol = blockIdx.x * 256 + threadIdx.x;
  for (int i = threadIdx.x; i < 800; i += 256) {
    const int ee = i / 100, f = i - ee * 100;
    xs[ee][f] = nan2num(x[((size_t)(SEP + e0 + ee) * BB + b) * FIN + f]);
  }
  __syncthreads();
  float acc[8];
#pragma unroll
  for (int i = 0; i < 8; ++i) acc[i] = 0.f;
  for (int f = 0; f < FIN; ++f) {
    const float w = w1[(size_t)b * (FIN * HHN) + (size_t)f * HHN + hcol];
#pragma unroll
    for (int ee = 0; ee < 8; ++ee) acc[ee] = fmaf(xs[ee][f], w, acc[ee]);
  }
  const float bias = b1[b * HHN + hcol];
#pragma unroll
  for (int ee = 0; ee < 8; ++ee)
    h1[((size_t)(e0 + ee) * BB + b) * HHN + hcol] = fmaxf(acc[ee] + bias, 0.f);
}

// eval2: out[eb][o] = h1[eb][:] @ w2[b][:,o] + b2[b][o].
// block = (64 eb-rows for one b) x 4 k-slices; w2 for b staged in LDS
// (broadcast reads), partial reduce across k-slices in LDS.  grid (16, 16).
__global__ __launch_bounds__(256)
void eval2_kernel(const float* __restrict__ h1, const float* __restrict__ w2,
                  const float* __restrict__ b2, float* __restrict__ outp) {
  __shared__ float w2s[10][512];
  __shared__ float red[4][64][10];
  const int b = blockIdx.y;
  const int e0 = blockIdx.x * 64;
  const int tid = threadIdx.x;
  const int r = tid & 63, ks = tid >> 6;
  for (int i = tid; i < 5120; i += 256) {
    const int o = i >> 9, k = i & 511;
    w2s[o][k] = w2[(size_t)b * (HHN * NOUTN) + k * NOUTN + o];
  }
  __syncthreads();
  const int eb = (e0 + r) * BB + b;
  const float* hp = h1 + (size_t)eb * HHN + ks * 128;
  float acc[10];
#pragma unroll
  for (int o = 0; o < 10; ++o) acc[o] = 0.f;
  for (int kk = 0; kk < 128; kk += 4) {
    const float4 h4 = *(const float4*)&hp[kk];
#pragma unroll
    for (int o = 0; o < 10; ++o) {
      const float4 w4 = *(const float4*)&w2s[o][ks * 128 + kk];
      acc[o] = fmaf(h4.x, w4.x, acc[o]);
      acc[o] = fmaf(h4.y, w4.y, acc[o]);
      acc[o] = fmaf(h4.z, w4.z, acc[o]);
      acc[o] = fmaf(h4.w, w4.w, acc[o]);
    }
  }
#pragma unroll
  for (int o = 0; o < 10; ++o) red[ks][r][o] = acc[o];
  __syncthreads();
  if (ks == 0) {
#pragma unroll
    for (int o = 0; o < 10; ++o)
      outp[(size_t)eb * NOUTN + o] = red[0][r][o] + red[1][r][o] +
                                     red[2][r][o] + red[3][r][o] +
                                     b2[b * NOUTN + o];
  }
}

// ---------------------------------------------------------------------------
extern "C" void kernel_launch(void* const* d_in, const int* in_sizes, int n_in,
                              void* d_out, int out_size, void* d_ws, size_t ws_size,
                              hipStream_t stream) {
  const float* x      = (const float*)d_in[0];
  const float* y      = (const float*)d_in[1];
  const float* enc_W  = (const float*)d_in[2];
  const float* enc_b  = (const float*)d_in[3];
  const float* yenc_W = (const float*)d_in[4];
  const float* yenc_b = (const float*)d_in[5];
  const float* Wq     = (const float*)d_in[6];
  const float* Wk     = (const float*)d_in[7];
  const float* Wv     = (const float*)d_in[8];
  const float* Wo     = (const float*)d_in[9];
  const float* ln1_g  = (const float*)d_in[10];
  const float* ln1_b  = (const float*)d_in[11];
  const float* ln2_g  = (const float*)d_in[12];
  const float* ln2_b  = (const float*)d_in[13];
  const float* ffn_W1 = (const float*)d_in[14];
  const float* ffn_b1 = (const float*)d_in[15];
  const float* ffn_W2 = (const float*)d_in[16];
  const float* ffn_b2 = (const float*)d_in[17];
  const float* dec_W  = (const float*)d_in[18];
  const float* dec_b  = (const float*)d_in[19];
  const float* hw1    = (const float*)d_in[20];
  const float* hb1    = (const float*)d_in[21];
  const float* hw2    = (const float*)d_in[22];
  const float* hb2    = (const float*)d_in[23];

  char* ws = (char*)d_ws;
  // Arena (lifetimes disjoint where overlapped):
  unsigned short* ff1b  = (unsigned short*)(ws + 0 * MB);    // 64MB (FFN1-FFN2)
  unsigned short* xb    = (unsigned short*)(ws + 0 * MB);    //  4MB (enc)
  float*          pp    = (float*)(ws + 0 * MB);             // 512KB (pool, post-FFN)
  float*          pd    = (float*)(ws + 1 * MB);             // 256KB (dec)
  float*          hgp   = (float*)(ws + 2 * MB);             // 26.2MB (head partials)
  unsigned short* txb   = (unsigned short*)(ws + 16 * MB);   // 16MB
  unsigned short* vt    = (unsigned short*)(ws + 32 * MB);   // 16MB
  unsigned short* aob   = (unsigned short*)(ws + 48 * MB);   // 16MB
  unsigned short* qkvb  = (unsigned short*)(ws + 64 * MB);   // 48MB
  float*          z32   = (float*)(ws + 64 * MB);            // 32MB (post-attn)
  unsigned short* zb    = (unsigned short*)(ws + 96 * MB);   // 16MB
  float*          tx32  = (float*)(ws + 112 * MB);           // 32MB
  float*          ff2   = (float*)(ws + 112 * MB);           // 32MB
  float*          aop   = (float*)(ws + 144 * MB);           // 32MB
  float*          outb  = (float*)(ws + 144 * MB);           // 32MB
  float*          h1    = (float*)(ws + 144 * MB);           // 32MB (eval)
  size_t wo_ = 176 * (size_t)MB;
  unsigned short* WencT = (unsigned short*)(ws + wo_); wo_ += (size_t)EE * FINP * 2;
  unsigned short* WqkvT = (unsigned short*)(ws + wo_); wo_ += (size_t)3 * EE * EE * 2;
  unsigned short* WoT   = (unsigned short*)(ws + wo_); wo_ += (size_t)EE * EE * 2;
  unsigned short* W1T   = (unsigned short*)(ws + wo_); wo_ += (size_t)FFNN * EE * 2;
  unsigned short* W2T   = (unsigned short*)(ws + wo_); wo_ += (size_t)EE * FFNN * 2;
  float* pooled = (float*)(ws + wo_); wo_ += (size_t)BB * EE * 4;
  float* dh     = (float*)(ws + wo_); wo_ += (size_t)BB * DECN * 4;
  float* w1g    = (float*)(ws + wo_); wo_ += (size_t)BB * FIN * HHN * 4;
  float* b1g    = (float*)(ws + wo_); wo_ += (size_t)BB * HHN * 4;
  float* w2g    = (float*)(ws + wo_); wo_ += (size_t)BB * HHN * NOUTN * 4;
  float* b2g    = (float*)(ws + wo_);
  float* outp = (float*)d_out;

  // 0) weight prep (bf16, transposed [N][K])
  transcast<<<dim3(EE / 32, FINP / 32), dim3(32, 8), 0, stream>>>(enc_W, WencT, FIN, EE, FINP);
  transcast<<<dim3(EE / 32, EE / 32), dim3(32, 8), 0, stream>>>(Wq, WqkvT, EE, EE, EE);
  transcast<<<dim3(EE / 32, EE / 32), dim3(32, 8), 0, stream>>>(Wk, WqkvT + (size_t)EE * EE, EE, EE, EE);
  transcast<<<dim3(EE / 32, EE / 32), dim3(32, 8), 0, stream>>>(Wv, WqkvT + (size_t)2 * EE * EE, EE, EE, EE);
  transcast<<<dim3(EE / 32, EE / 32), dim3(32, 8), 0, stream>>>(Wo, WoT, EE, EE, EE);
  transcast<<<dim3(FFNN / 32, EE / 32), dim3(32, 8), 0, stream>>>(ffn_W1, W1T, EE, FFNN, EE);
  transcast<<<dim3(EE / 32, FFNN / 32), dim3(32, 8), 0, stream>>>(ffn_W2, W2T, FFNN, EE, FFNN);
  castx_kernel<<<(TBR * FINP) / 256, 256, 0, stream>>>(x, xb);

  // 1) encoder
  gemm_bf16<true, false, false, true, true><<<dim3(EE / 128, TBR / 128), 256, 0, stream>>>(
      xb, WencT, tx32, txb, enc_b, yenc_b, y, yenc_W, TBR, EE, FINP);
  // 2) fused QKV
  gemm_bf16<false, false, false, false, true><<<dim3(1536 / 128, TBR / 128), 256, 0, stream>>>(
      txb, WqkvT, nullptr, qkvb, nullptr, nullptr, nullptr, nullptr, TBR, 1536, EE);
  // 3) V transpose
  vtrans<<<dim3(SEP / 64, NHH, BB), 256, 0, stream>>>(qkvb, vt);
  // 4) flash attention
  attn_mfma<<<dim3(SEP / 64, NHH, BB), 256, 0, stream>>>(qkvb, vt, aob);
  // 5) Wo projection
  gemm_bf16<false, false, false, true, false><<<dim3(EE / 128, TBR / 128), 256, 0, stream>>>(
      aob, WoT, aop, nullptr, nullptr, nullptr, nullptr, nullptr, TBR, EE, EE);
  // 6) LN1
  ln_k<true><<<TBR, 256, 0, stream>>>(tx32, aop, ln1_g, ln1_b, z32, zb);
  // 7) FFN1
  gemm_bf16<false, true, true, false, true><<<dim3(FFNN / 128, TBR / 128), 256, 0, stream>>>(
      zb, W1T, nullptr, ff1b, ffn_b1, nullptr, nullptr, nullptr, TBR, FFNN, EE);
  // 8) FFN2
  gemm_bf16<false, true, false, true, false><<<dim3(EE / 128, TBR / 128), 256, 0, stream>>>(
      ff1b, W2T, ff2, nullptr, ffn_b2, nullptr, nullptr, nullptr, TBR, EE, FFNN);
  // 9) LN2
  ln_k<false><<<TBR, 256, 0, stream>>>(z32, ff2, ln2_g, ln2_b, outb, nullptr);
  // 10) decoder: pool (T-split), dec (K-split), head GEMMs (K-split)
  pool1<<<dim3(32, 16), 256, 0, stream>>>(outb, pp);
  pool2<<<32, 256, 0, stream>>>(pp, pooled);
  dec1<<<dim3(4, BB), 256, 0, stream>>>(pooled, dec_W, pd);
  dec2<<<64, 256, 0, stream>>>(pd, dec_b, dh);
  hgemm_split<128><<<dim3(50, 8), 256, 0, stream>>>(dh, hw1, hgp, FIN * HHN);
  hg_reduce<<<800, 256, 0, stream>>>(hgp, w1g, BB * FIN * HHN, 8);
  hgemm_split<64><<<dim3(5, 16), 256, 0, stream>>>(dh, hw2, hgp, HHN * NOUTN);
  hg_reduce<<<80, 256, 0, stream>>>(hgp, w2g, BB * HHN * NOUTN, 16);
  hgemm_split<64><<<dim3(1, 16), 256, 0, stream>>>(dh, hb1, hgp, HHN);
  hg_reduce<<<8, 256, 0, stream>>>(hgp, b1g, BB * HHN, 16);
  hgemm_split<64><<<dim3(1, 16), 256, 0, stream>>>(dh, hb2, hgp, NOUTN);
  hg_reduce<<<1, 256, 0, stream>>>(hgp, b2g, BB * NOUTN, 16);
  // 11) generated per-batch MLP on eval tokens
  eval1_kernel<<<dim3(HHN / 256, EVALN / 8, BB), 256, 0, stream>>>(x, w1g, b1g, h1);
  eval2_kernel<<<dim3(EVALN / 64, BB), 256, 0, stream>>>(h1, w2g, b2g, outp);
}

// Round 4
// 863.635 us; speedup vs baseline: 5.9282x; 1.0181x over previous
//
#include <hip/hip_runtime.h>
#include <math.h>

// Problem constants: S=2048, B=16, F=100, E=512, NH=8, DH=64, FF=2048,
// DEC=1024, H=512, NOUT=10, sep=1024 (structural).
#define SEP   1024
#define EVALN 1024
#define BB    16
#define FIN   100
#define FINP  128          // F padded to 128 for bf16 GEMM (zeros)
#define EE    512
#define NHH   8
#define DHH   64
#define FFNN  2048
#define DECN  1024
#define HHN   512
#define NOUTN 10
#define TBR   (SEP * BB)   // 16384 token rows
#define MB    (1024u * 1024u)

typedef short  s16x8 __attribute__((ext_vector_type(8)));
typedef float  f32x4 __attribute__((ext_vector_type(4)));

__device__ __forceinline__ unsigned short f2b(float f) {
  union { float f; unsigned int u; } v; v.f = f;
  unsigned int u = v.u;
  return (unsigned short)((u + 0x7fffu + ((u >> 16) & 1u)) >> 16);
}

__device__ __forceinline__ float nan2num(float v) {
  if (isnan(v)) return 0.f;
  if (isinf(v)) return v > 0.f ? 3.4028234663852886e38f : -3.4028234663852886e38f;
  return v;
}

// ---------------------------------------------------------------------------
// Weight transpose+cast: W[K][N] f32 -> Wt[N][Kp] bf16 (zero-padded K..Kp).
// ---------------------------------------------------------------------------
__global__ __launch_bounds__(256)
void transcast(const float* __restrict__ W, unsigned short* __restrict__ Wt,
               int K, int N, int Kp) {
  __shared__ float t[32][33];
  const int n0 = blockIdx.x * 32, k0 = blockIdx.y * 32;
  const int tx = threadIdx.x, ty = threadIdx.y;
#pragma unroll
  for (int r = 0; r < 4; ++r) {
    const int k = k0 + ty + r * 8;
    t[ty + r * 8][tx] = (k < K) ? W[(size_t)k * N + n0 + tx] : 0.f;
  }
  __syncthreads();
#pragma unroll
  for (int r = 0; r < 4; ++r) {
    const int n = n0 + ty + r * 8;
    Wt[(size_t)n * Kp + k0 + tx] = f2b(t[tx][ty + r * 8]);
  }
}

// x[:sep] f32 [16384][100] -> xb bf16 [16384][128] (zero-padded)
__global__ __launch_bounds__(256)
void castx_kernel(const float* __restrict__ x, unsigned short* __restrict__ xb) {
  const int idx = blockIdx.x * 256 + threadIdx.x;
  const int m = idx >> 7, f = idx & 127;
  xb[idx] = (f < FIN) ? f2b(x[(size_t)m * FIN + f]) : (unsigned short)0;
}

// ---------------------------------------------------------------------------
// bf16 MFMA GEMM: C[M,N] = A[M,K](bf16) @ Bt[N,K](bf16)^T  + epilogue.
// ---------------------------------------------------------------------------
template <bool YENC, bool BIAS, bool RELU, bool OF32, bool OB16>
__global__ __launch_bounds__(256)
void gemm_bf16(const unsigned short* __restrict__ A,
               const unsigned short* __restrict__ Bt,
               float* __restrict__ C32, unsigned short* __restrict__ C16,
               const float* __restrict__ bias, const float* __restrict__ yb2,
               const float* __restrict__ yvec, const float* __restrict__ yW,
               int M, int N, int K) {
  __shared__ unsigned short As[128][40];
  __shared__ unsigned short Bs[128][40];
  const int tid = threadIdx.x;
  const int wave = tid >> 6, lane = tid & 63;
  const int q = lane >> 4, c = lane & 15;
  const int wm = wave >> 1, wn = wave & 1;
  const int m0 = blockIdx.y * 128, n0 = blockIdx.x * 128;
  const int sr = tid >> 1;
  const int so = (tid & 1) * 16;

  f32x4 acc[4][4];
#pragma unroll
  for (int i = 0; i < 4; ++i)
#pragma unroll
    for (int j = 0; j < 4; ++j) acc[i][j] = (f32x4){0.f, 0.f, 0.f, 0.f};

  for (int k0 = 0; k0 < K; k0 += 32) {
    const uint4* ga = (const uint4*)(A + (size_t)(m0 + sr) * K + k0 + so);
    const uint4 a0 = ga[0], a1 = ga[1];
    const uint4* gb = (const uint4*)(Bt + (size_t)(n0 + sr) * K + k0 + so);
    const uint4 b0 = gb[0], b1 = gb[1];
    __syncthreads();
    *(uint4*)&As[sr][so] = a0; *(uint4*)&As[sr][so + 8] = a1;
    *(uint4*)&Bs[sr][so] = b0; *(uint4*)&Bs[sr][so + 8] = b1;
    __syncthreads();
    s16x8 af[4], bf[4];
#pragma unroll
    for (int mi = 0; mi < 4; ++mi)
      af[mi] = *(const s16x8*)&As[wm * 64 + mi * 16 + c][q * 8];
#pragma unroll
    for (int ni = 0; ni < 4; ++ni)
      bf[ni] = *(const s16x8*)&Bs[wn * 64 + ni * 16 + c][q * 8];
#pragma unroll
    for (int mi = 0; mi < 4; ++mi)
#pragma unroll
      for (int ni = 0; ni < 4; ++ni)
        acc[mi][ni] = __builtin_amdgcn_mfma_f32_16x16x32_bf16(
            af[mi], bf[ni], acc[mi][ni], 0, 0, 0);
  }

  float bb[4], yw[4];
#pragma unroll
  for (int ni = 0; ni < 4; ++ni) {
    const int n = n0 + wn * 64 + ni * 16 + c;
    float t = 0.f;
    if (BIAS) t = bias[n];
    if (YENC) t = bias[n] + yb2[n];
    bb[ni] = t;
    yw[ni] = YENC ? yW[n] : 0.f;
  }
#pragma unroll
  for (int mi = 0; mi < 4; ++mi) {
#pragma unroll
    for (int r = 0; r < 4; ++r) {
      const int m = m0 + wm * 64 + mi * 16 + q * 4 + r;
      const float yv = YENC ? yvec[m] : 0.f;
#pragma unroll
      for (int ni = 0; ni < 4; ++ni) {
        const int n = n0 + wn * 64 + ni * 16 + c;
        float val = acc[mi][ni][r] + bb[ni];
        if (YENC) val = fmaf(yv, yw[ni], val);
        if (RELU) val = fmaxf(val, 0.f);
        if (OF32) C32[(size_t)m * N + n] = val;
        if (OB16) C16[(size_t)m * N + n] = f2b(val);
      }
    }
  }
}

// ---------------------------------------------------------------------------
// V transpose for PV B-operand, with the s-axis PV swizzle baked in:
// within each 64-s block, phys position p holds logical s = 16*(p&3)+(p>>2).
// P is written with the same permutation, so PV's MFMA k-sum is exact.
// ---------------------------------------------------------------------------
__global__ __launch_bounds__(256)
void vtrans(const unsigned short* __restrict__ qkv, unsigned short* __restrict__ vt) {
  __shared__ unsigned short t[64][72];   // t[d][s_local]
  const int s0 = blockIdx.x * 64;
  const int h = blockIdx.y, b = blockIdx.z;
  const int tid = threadIdx.x;
  const int r = tid >> 2, o = (tid & 3) * 16;
  const unsigned short* g =
      qkv + ((size_t)(s0 + r) * BB + b) * 1536 + 1024 + h * 64 + o;
  unsigned short tmp[16];
  *(uint4*)tmp = *(const uint4*)g;
  *(uint4*)(tmp + 8) = *(const uint4*)(g + 8);
#pragma unroll
  for (int i = 0; i < 16; ++i) t[o + i][r] = tmp[i];   // t[d][s] = V[s][d]
  __syncthreads();
  // phase 2: thread (r=d, o=s-chunk) emits phys positions o..o+15
  unsigned short tmp2[16];
#pragma unroll
  for (int i = 0; i < 16; ++i) {
    const int p = o + i;
    tmp2[i] = t[r][16 * (p & 3) + (p >> 2)];
  }
  unsigned short* out =
      vt + ((size_t)(b * NHH + h) * 64 + r) * 1024 + s0 + o;
  *(uint4*)out = *(const uint4*)&tmp2[0];
  *(uint4*)(out + 8) = *(const uint4*)&tmp2[8];
}

// ---------------------------------------------------------------------------
// Flash attention, bf16 MFMA.  Grid (hb=128, t0/64=16): id%8 = hb%8 so all
// t0-blocks of one (b,h) share an XCD -> K/V L2-resident.  Per s-tile:
// prefetch next K/V to regs, QK mfma, online softmax, packed ds_write_b64 of
// swizzled P (wave-private, NO barrier), PV mfma, 2 barriers total.
// ---------------------------------------------------------------------------
__global__ __launch_bounds__(256)
void attn_mfma(const unsigned short* __restrict__ qkv,
               const unsigned short* __restrict__ vt,
               unsigned short* __restrict__ aob) {
  __shared__ unsigned short Qs[64][72];
  __shared__ unsigned short Ks[64][72];
  __shared__ unsigned short Vts[64][72];
  __shared__ unsigned short Pls[4][16][72];
  const int tid = threadIdx.x;
  const int w = tid >> 6, lane = tid & 63;
  const int q = lane >> 4, c = lane & 15;
  const int hb = blockIdx.x;
  const int h = hb & (NHH - 1), b = hb >> 3;
  const int t0 = blockIdx.y * 64;
  const int bh = b * NHH + h;
  const int sr = tid >> 2, so = (tid & 3) * 16;

  {
    const unsigned short* g =
        qkv + ((size_t)(t0 + sr) * BB + b) * 1536 + h * 64 + so;
    *(uint4*)&Qs[sr][so] = *(const uint4*)g;
    *(uint4*)&Qs[sr][so + 8] = *(const uint4*)(g + 8);
  }
  __syncthreads();
  s16x8 aq[2];
  aq[0] = *(const s16x8*)&Qs[w * 16 + c][q * 8];
  aq[1] = *(const s16x8*)&Qs[w * 16 + c][32 + q * 8];

  float m_s[4], l_s[4];
  f32x4 oacc[4];
#pragma unroll
  for (int r = 0; r < 4; ++r) { m_s[r] = -3.0e38f; l_s[r] = 0.f; }
#pragma unroll
  for (int dt = 0; dt < 4; ++dt) oacc[dt] = (f32x4){0.f, 0.f, 0.f, 0.f};

  // prefetch + stage tile 0
  uint4 kr0, kr1, vr0, vr1;
  {
    const unsigned short* gk =
        qkv + ((size_t)sr * BB + b) * 1536 + 512 + h * 64 + so;
    kr0 = *(const uint4*)gk; kr1 = *(const uint4*)(gk + 8);
    const unsigned short* gv = vt + ((size_t)bh * 64 + sr) * 1024 + so;
    vr0 = *(const uint4*)gv; vr1 = *(const uint4*)(gv + 8);
  }
  *(uint4*)&Ks[sr][so] = kr0; *(uint4*)&Ks[sr][so + 8] = kr1;
  *(uint4*)&Vts[sr][so] = vr0; *(uint4*)&Vts[sr][so + 8] = vr1;
  __syncthreads();

  for (int s0 = 0; s0 < SEP; s0 += 64) {
    const bool more = (s0 + 64 < SEP);
    if (more) {  // prefetch next tile into regs (latency hidden under compute)
      const unsigned short* gk =
          qkv + ((size_t)(s0 + 64 + sr) * BB + b) * 1536 + 512 + h * 64 + so;
      kr0 = *(const uint4*)gk; kr1 = *(const uint4*)(gk + 8);
      const unsigned short* gv =
          vt + ((size_t)bh * 64 + sr) * 1024 + s0 + 64 + so;
      vr0 = *(const uint4*)gv; vr1 = *(const uint4*)(gv + 8);
    }
    // S = Q K^T for this wave's 16 rows x 64 cols
    f32x4 sacc[4];
#pragma unroll
    for (int ch = 0; ch < 4; ++ch) sacc[ch] = (f32x4){0.f, 0.f, 0.f, 0.f};
#pragma unroll
    for (int ch = 0; ch < 4; ++ch) {
#pragma unroll
      for (int kh = 0; kh < 2; ++kh) {
        s16x8 bk = *(const s16x8*)&Ks[ch * 16 + c][kh * 32 + q * 8];
        sacc[ch] = __builtin_amdgcn_mfma_f32_16x16x32_bf16(
            aq[kh], bk, sacc[ch], 0, 0, 0);
      }
    }
    // online softmax (rows q*4+r, cols ch*16+c)
    float rmax[4];
#pragma unroll
    for (int r = 0; r < 4; ++r) {
      float mx = -3.0e38f;
#pragma unroll
      for (int ch = 0; ch < 4; ++ch) mx = fmaxf(mx, sacc[ch][r] * 0.125f);
      rmax[r] = mx;
    }
#pragma unroll
    for (int mask = 1; mask < 16; mask <<= 1)
#pragma unroll
      for (int r = 0; r < 4; ++r)
        rmax[r] = fmaxf(rmax[r], __shfl_xor(rmax[r], mask));
    float alpha[4], rsum[4];
    float p[4][4];
#pragma unroll
    for (int r = 0; r < 4; ++r) {
      const float mnew = fmaxf(m_s[r], rmax[r]);
      alpha[r] = __expf(m_s[r] - mnew);
      float sum = 0.f;
#pragma unroll
      for (int ch = 0; ch < 4; ++ch) {
        const float pv = __expf(sacc[ch][r] * 0.125f - mnew);
        p[ch][r] = pv;
        sum += pv;
      }
      rsum[r] = sum;
      m_s[r] = mnew;
    }
#pragma unroll
    for (int mask = 1; mask < 16; mask <<= 1)
#pragma unroll
      for (int r = 0; r < 4; ++r) rsum[r] += __shfl_xor(rsum[r], mask);
#pragma unroll
    for (int r = 0; r < 4; ++r) l_s[r] = l_s[r] * alpha[r] + rsum[r];
#pragma unroll
    for (int dt = 0; dt < 4; ++dt)
#pragma unroll
      for (int r = 0; r < 4; ++r) oacc[dt][r] *= alpha[r];
    // packed swizzled P write: phys kp=4c+ch holds logical s=16ch+c.
    // Wave-private strip -> no barrier; lgkmcnt orders write->read in-wave.
#pragma unroll
    for (int r = 0; r < 4; ++r) {
      uint2 pk;
      pk.x = (unsigned)f2b(p[0][r]) | ((unsigned)f2b(p[1][r]) << 16);
      pk.y = (unsigned)f2b(p[2][r]) | ((unsigned)f2b(p[3][r]) << 16);
      *(uint2*)&Pls[w][q * 4 + r][c * 4] = pk;
    }
    // O += P @ V  (both P and Vts s-axes carry the same permutation)
#pragma unroll
    for (int kh = 0; kh < 2; ++kh) {
      s16x8 ap = *(const s16x8*)&Pls[w][c][kh * 32 + q * 8];
#pragma unroll
      for (int dt = 0; dt < 4; ++dt) {
        s16x8 bv = *(const s16x8*)&Vts[dt * 16 + c][kh * 32 + q * 8];
        oacc[dt] = __builtin_amdgcn_mfma_f32_16x16x32_bf16(
            ap, bv, oacc[dt], 0, 0, 0);
      }
    }
    __syncthreads();            // all waves done reading Ks/Vts
    if (more) {
      *(uint4*)&Ks[sr][so] = kr0; *(uint4*)&Ks[sr][so + 8] = kr1;
      *(uint4*)&Vts[sr][so] = vr0; *(uint4*)&Vts[sr][so + 8] = vr1;
      __syncthreads();
    }
  }
  float inv[4];
#pragma unroll
  for (int r = 0; r < 4; ++r) inv[r] = 1.f / l_s[r];
#pragma unroll
  for (int dt = 0; dt < 4; ++dt) {
#pragma unroll
    for (int r = 0; r < 4; ++r) {
      const int m = t0 + w * 16 + q * 4 + r;
      aob[((size_t)m * BB + b) * EE + h * 64 + dt * 16 + c] =
          f2b(oacc[dt][r] * inv[r]);
    }
  }
}

// ---------------------------------------------------------------------------
// LayerNorm: o = LN(a + r) * g + be.  Optionally also emit bf16 copy.
// ---------------------------------------------------------------------------
template <bool B16>
__global__ __launch_bounds__(256)
void ln_k(const float* __restrict__ a, const float* __restrict__ r_,
          const float* __restrict__ g, const float* __restrict__ be,
          float* __restrict__ o32, unsigned short* __restrict__ o16) {
  __shared__ float ss[4], sqs[4];
  const int row = blockIdx.x;
  const int tid = threadIdx.x;
  const size_t base = (size_t)row * EE;
  const float x0 = a[base + tid] + r_[base + tid];
  const float x1 = a[base + tid + 256] + r_[base + tid + 256];
  float s = x0 + x1;
  float sq = x0 * x0 + x1 * x1;
#pragma unroll
  for (int off = 32; off >= 1; off >>= 1) {
    s += __shfl_xor(s, off);
    sq += __shfl_xor(sq, off);
  }
  const int wid = tid >> 6;
  if ((tid & 63) == 0) { ss[wid] = s; sqs[wid] = sq; }
  __syncthreads();
  s = ss[0] + ss[1] + ss[2] + ss[3];
  sq = sqs[0] + sqs[1] + sqs[2] + sqs[3];
  const float mean = s * (1.f / 512.f);
  const float var = sq * (1.f / 512.f) - mean * mean;
  const float rstd = rsqrtf(fmaxf(var, 0.f) + 1e-5f);
  const float v0 = (x0 - mean) * rstd * g[tid] + be[tid];
  const float v1 = (x1 - mean) * rstd * g[tid + 256] + be[tid + 256];
  o32[base + tid] = v0;
  o32[base + tid + 256] = v1;
  if (B16) {
    o16[base + tid] = f2b(v0);
    o16[base + tid + 256] = f2b(v1);
  }
}

// ---------------------------------------------------------------------------
// Decoder tail — K-split partials + reduce (latency-bound fixes).
// ---------------------------------------------------------------------------
__global__ __launch_bounds__(256)
void pool1(const float* __restrict__ outb, float* __restrict__ pp) {
  const int i = blockIdx.x * 256 + threadIdx.x;      // < 8192
  const int ts = blockIdx.y;
  const float* p = outb + (size_t)ts * 64 * (BB * EE) + i;
  float s0 = 0.f, s1 = 0.f, s2 = 0.f, s3 = 0.f;
  for (int t = 0; t < 64; t += 4) {
    s0 += p[(size_t)(t + 0) * (BB * EE)];
    s1 += p[(size_t)(t + 1) * (BB * EE)];
    s2 += p[(size_t)(t + 2) * (BB * EE)];
    s3 += p[(size_t)(t + 3) * (BB * EE)];
  }
  pp[ts * (BB * EE) + i] = (s0 + s1) + (s2 + s3);
}

__global__ __launch_bounds__(256)
void pool2(const float* __restrict__ pp, float* __restrict__ pooled) {
  const int i = blockIdx.x * 256 + threadIdx.x;
  float s = 0.f;
#pragma unroll
  for (int ts = 0; ts < 16; ++ts) s += pp[ts * (BB * EE) + i];
  pooled[i] = s * (1.f / (float)SEP);
}

__global__ __launch_bounds__(256)
void dec1(const float* __restrict__ pooled, const float* __restrict__ dW,
          float* __restrict__ pd) {
  __shared__ float ps[128];
  const int ks = blockIdx.x, b = blockIdx.y;
  const int tid = threadIdx.x;
  if (tid < 128) ps[tid] = pooled[b * EE + ks * 128 + tid];
  __syncthreads();
  const int n = tid * 4;
  float4 acc = {0.f, 0.f, 0.f, 0.f};
  for (int kk = 0; kk < 128; kk += 4) {
    const float4 p4 = *(const float4*)&ps[kk];
#pragma unroll
    for (int i = 0; i < 4; ++i) {
      const float4 w4 = *(const float4*)&dW[(size_t)(ks * 128 + kk + i) * DECN + n];
      const float pv = (i == 0) ? p4.x : (i == 1) ? p4.y : (i == 2) ? p4.z : p4.w;
      acc.x = fmaf(pv, w4.x, acc.x); acc.y = fmaf(pv, w4.y, acc.y);
      acc.z = fmaf(pv, w4.z, acc.z); acc.w = fmaf(pv, w4.w, acc.w);
    }
  }
  *(float4*)&pd[(size_t)(ks * BB + b) * DECN + n] = acc;
}

__global__ __launch_bounds__(256)
void dec2(const float* __restrict__ pd, const float* __restrict__ db,
          float* __restrict__ dh) {
  const int idx = blockIdx.x * 256 + threadIdx.x;    // < 16384
  const int b = idx >> 10, n = idx & 1023;
  float s = db[n];
#pragma unroll
  for (int ks = 0; ks < 4; ++ks) s += pd[(size_t)(ks * BB + b) * DECN + n];
  dh[idx] = fmaxf(s, 0.f);
}

template <int KL>
__global__ __launch_bounds__(256)
void hgemm_split(const float* __restrict__ dh, const float* __restrict__ W,
                 float* __restrict__ part, int N) {
  __shared__ float dhs[16][KL];
  const int tid = threadIdx.x;
  const int n0 = blockIdx.x * 1024;
  const int k0 = blockIdx.y * KL;
  for (int i = tid; i < 16 * (KL / 4); i += 256) {
    const int b = i / (KL / 4), kq = i % (KL / 4);
    *(float4*)&dhs[b][kq * 4] = *(const float4*)&dh[b * DECN + k0 + kq * 4];
  }
  __syncthreads();
  float* pb = part + (size_t)blockIdx.y * 16 * N;
  if ((N & 3) == 0) {
    const int n = n0 + tid * 4;
    if (n + 3 < N) {
      float4 acc[16];
#pragma unroll
      for (int b = 0; b < 16; ++b) acc[b] = (float4){0.f, 0.f, 0.f, 0.f};
      for (int kk = 0; kk < KL; kk += 4) {
        float4 w4[4];
#pragma unroll
        for (int i = 0; i < 4; ++i)
          w4[i] = *(const float4*)&W[(size_t)(k0 + kk + i) * N + n];
#pragma unroll
        for (int b = 0; b < 16; ++b) {
          const float4 d4 = *(const float4*)&dhs[b][kk];
          acc[b].x = fmaf(d4.x, w4[0].x, acc[b].x);
          acc[b].y = fmaf(d4.x, w4[0].y, acc[b].y);
          acc[b].z = fmaf(d4.x, w4[0].z, acc[b].z);
          acc[b].w = fmaf(d4.x, w4[0].w, acc[b].w);
          acc[b].x = fmaf(d4.y, w4[1].x, acc[b].x);
          acc[b].y = fmaf(d4.y, w4[1].y, acc[b].y);
          acc[b].z = fmaf(d4.y, w4[1].z, acc[b].z);
          acc[b].w = fmaf(d4.y, w4[1].w, acc[b].w);
          acc[b].x = fmaf(d4.z, w4[2].x, acc[b].x);
          acc[b].y = fmaf(d4.z, w4[2].y, acc[b].y);
          acc[b].z = fmaf(d4.z, w4[2].z, acc[b].z);
          acc[b].w = fmaf(d4.z, w4[2].w, acc[b].w);
          acc[b].x = fmaf(d4.w, w4[3].x, acc[b].x);
          acc[b].y = fmaf(d4.w, w4[3].y, acc[b].y);
          acc[b].z = fmaf(d4.w, w4[3].z, acc[b].z);
          acc[b].w = fmaf(d4.w, w4[3].w, acc[b].w);
        }
      }
#pragma unroll
      for (int b = 0; b < 16; ++b) *(float4*)&pb[(size_t)b * N + n] = acc[b];
    }
  } else {
    const int n = n0 + tid;
    if (n < N) {
      float acc[16];
#pragma unroll
      for (int b = 0; b < 16; ++b) acc[b] = 0.f;
      for (int kk = 0; kk < KL; ++kk) {
        const float w = W[(size_t)(k0 + kk) * N + n];
#pragma unroll
        for (int b = 0; b < 16; ++b) acc[b] = fmaf(dhs[b][kk], w, acc[b]);
      }
#pragma unroll
      for (int b = 0; b < 16; ++b) pb[(size_t)b * N + n] = acc[b];
    }
  }
}

__global__ __launch_bounds__(256)
void hg_reduce(const float* __restrict__ part, float* __restrict__ out,
               int total, int S) {
  const int i4 = (blockIdx.x * 256 + threadIdx.x) * 4;
  if (i4 >= total) return;
  float4 s = *(const float4*)&part[i4];
  for (int p = 1; p < S; ++p) {
    const float4 v = *(const float4*)&part[(size_t)p * total + i4];
    s.x += v.x; s.y += v.y; s.z += v.z; s.w += v.w;
  }
  *(float4*)&out[i4] = s;
}

// h1[e,b,h] = relu(nan2num(x[sep+e,b,:]) @ w1[b,:,h] + b1[b,h])
__global__ __launch_bounds__(256)
void eval1_kernel(const float* __restrict__ x, const float* __restrict__ w1,
                  const float* __restrict__ b1, float* __restrict__ h1) {
  __shared__ float xs[8][100];
  const int b = blockIdx.z;
  const int e0 = blockIdx.y << 3;
  const int hcol = blockIdx.x * 256 + threadIdx.x;
  for (int i = threadIdx.x; i < 800; i += 256) {
    const int ee = i / 100, f = i - ee * 100;
    xs[ee][f] = nan2num(x[((size_t)(SEP + e0 + ee) * BB + b) * FIN + f]);
  }
  __syncthreads();
  float acc[8];
#pragma unroll
  for (int i = 0; i < 8; ++i) acc[i] = 0.f;
  for (int f = 0; f < FIN; ++f) {
    const float w = w1[(size_t)b * (FIN * HHN) + (size_t)f * HHN + hcol];
#pragma unroll
    for (int ee = 0; ee < 8; ++ee) acc[ee] = fmaf(xs[ee][f], w, acc[ee]);
  }
  const float bias = b1[b * HHN + hcol];
#pragma unroll
  for (int ee = 0; ee < 8; ++ee)
    h1[((size_t)(e0 + ee) * BB + b) * HHN + hcol] = fmaxf(acc[ee] + bias, 0.f);
}

// eval2: per-(b, 64 rows) block, w2 staged in LDS, 4-way K-split + LDS reduce
__global__ __launch_bounds__(256)
void eval2_kernel(const float* __restrict__ h1, const float* __restrict__ w2,
                  const float* __restrict__ b2, float* __restrict__ outp) {
  __shared__ float w2s[10][512];
  __shared__ float red[4][64][10];
  const int b = blockIdx.y;
  const int e0 = blockIdx.x * 64;
  const int tid = threadIdx.x;
  const int r = tid & 63, ks = tid >> 6;
  for (int i = tid; i < 5120; i += 256) {
    const int o = i >> 9, k = i & 511;
    w2s[o][k] = w2[(size_t)b * (HHN * NOUTN) + k * NOUTN + o];
  }
  __syncthreads();
  const int eb = (e0 + r) * BB + b;
  const float* hp = h1 + (size_t)eb * HHN + ks * 128;
  float acc[10];
#pragma unroll
  for (int o = 0; o < 10; ++o) acc[o] = 0.f;
  for (int kk = 0; kk < 128; kk += 4) {
    const float4 h4 = *(const float4*)&hp[kk];
#pragma unroll
    for (int o = 0; o < 10; ++o) {
      const float4 w4 = *(const float4*)&w2s[o][ks * 128 + kk];
      acc[o] = fmaf(h4.x, w4.x, acc[o]);
      acc[o] = fmaf(h4.y, w4.y, acc[o]);
      acc[o] = fmaf(h4.z, w4.z, acc[o]);
      acc[o] = fmaf(h4.w, w4.w, acc[o]);
    }
  }
#pragma unroll
  for (int o = 0; o < 10; ++o) red[ks][r][o] = acc[o];
  __syncthreads();
  if (ks == 0) {
#pragma unroll
    for (int o = 0; o < 10; ++o)
      outp[(size_t)eb * NOUTN + o] = red[0][r][o] + red[1][r][o] +
                                     red[2][r][o] + red[3][r][o] +
                                     b2[b * NOUTN + o];
  }
}

// ---------------------------------------------------------------------------
extern "C" void kernel_launch(void* const* d_in, const int* in_sizes, int n_in,
                              void* d_out, int out_size, void* d_ws, size_t ws_size,
                              hipStream_t stream) {
  const float* x      = (const float*)d_in[0];
  const float* y      = (const float*)d_in[1];
  const float* enc_W  = (const float*)d_in[2];
  const float* enc_b  = (const float*)d_in[3];
  const float* yenc_W = (const float*)d_in[4];
  const float* yenc_b = (const float*)d_in[5];
  const float* Wq     = (const float*)d_in[6];
  const float* Wk     = (const float*)d_in[7];
  const float* Wv     = (const float*)d_in[8];
  const float* Wo     = (const float*)d_in[9];
  const float* ln1_g  = (const float*)d_in[10];
  const float* ln1_b  = (const float*)d_in[11];
  const float* ln2_g  = (const float*)d_in[12];
  const float* ln2_b  = (const float*)d_in[13];
  const float* ffn_W1 = (const float*)d_in[14];
  const float* ffn_b1 = (const float*)d_in[15];
  const float* ffn_W2 = (const float*)d_in[16];
  const float* ffn_b2 = (const float*)d_in[17];
  const float* dec_W  = (const float*)d_in[18];
  const float* dec_b  = (const float*)d_in[19];
  const float* hw1    = (const float*)d_in[20];
  const float* hb1    = (const float*)d_in[21];
  const float* hw2    = (const float*)d_in[22];
  const float* hb2    = (const float*)d_in[23];

  char* ws = (char*)d_ws;
  unsigned short* ff1b  = (unsigned short*)(ws + 0 * MB);    // 64MB (FFN1-FFN2)
  unsigned short* xb    = (unsigned short*)(ws + 0 * MB);    //  4MB (enc)
  float*          pp    = (float*)(ws + 0 * MB);             // 512KB (pool)
  float*          pd    = (float*)(ws + 1 * MB);             // 256KB (dec)
  float*          hgp   = (float*)(ws + 2 * MB);             // 26.2MB (head partials)
  unsigned short* txb   = (unsigned short*)(ws + 16 * MB);   // 16MB
  unsigned short* vt    = (unsigned short*)(ws + 32 * MB);   // 16MB
  unsigned short* aob   = (unsigned short*)(ws + 48 * MB);   // 16MB
  unsigned short* qkvb  = (unsigned short*)(ws + 64 * MB);   // 48MB
  float*          z32   = (float*)(ws + 64 * MB);            // 32MB (post-attn)
  unsigned short* zb    = (unsigned short*)(ws + 96 * MB);   // 16MB
  float*          tx32  = (float*)(ws + 112 * MB);           // 32MB
  float*          ff2   = (float*)(ws + 112 * MB);           // 32MB
  float*          aop   = (float*)(ws + 144 * MB);           // 32MB
  float*          outb  = (float*)(ws + 144 * MB);           // 32MB
  float*          h1    = (float*)(ws + 144 * MB);           // 32MB (eval)
  size_t wo_ = 176 * (size_t)MB;
  unsigned short* WencT = (unsigned short*)(ws + wo_); wo_ += (size_t)EE * FINP * 2;
  unsigned short* WqkvT = (unsigned short*)(ws + wo_); wo_ += (size_t)3 * EE * EE * 2;
  unsigned short* WoT   = (unsigned short*)(ws + wo_); wo_ += (size_t)EE * EE * 2;
  unsigned short* W1T   = (unsigned short*)(ws + wo_); wo_ += (size_t)FFNN * EE * 2;
  unsigned short* W2T   = (unsigned short*)(ws + wo_); wo_ += (size_t)EE * FFNN * 2;
  float* pooled = (float*)(ws + wo_); wo_ += (size_t)BB * EE * 4;
  float* dh     = (float*)(ws + wo_); wo_ += (size_t)BB * DECN * 4;
  float* w1g    = (float*)(ws + wo_); wo_ += (size_t)BB * FIN * HHN * 4;
  float* b1g    = (float*)(ws + wo_); wo_ += (size_t)BB * HHN * 4;
  float* w2g    = (float*)(ws + wo_); wo_ += (size_t)BB * HHN * NOUTN * 4;
  float* b2g    = (float*)(ws + wo_);
  float* outp = (float*)d_out;

  // 0) weight prep (bf16, transposed [N][K])
  transcast<<<dim3(EE / 32, FINP / 32), dim3(32, 8), 0, stream>>>(enc_W, WencT, FIN, EE, FINP);
  transcast<<<dim3(EE / 32, EE / 32), dim3(32, 8), 0, stream>>>(Wq, WqkvT, EE, EE, EE);
  transcast<<<dim3(EE / 32, EE / 32), dim3(32, 8), 0, stream>>>(Wk, WqkvT + (size_t)EE * EE, EE, EE, EE);
  transcast<<<dim3(EE / 32, EE / 32), dim3(32, 8), 0, stream>>>(Wv, WqkvT + (size_t)2 * EE * EE, EE, EE, EE);
  transcast<<<dim3(EE / 32, EE / 32), dim3(32, 8), 0, stream>>>(Wo, WoT, EE, EE, EE);
  transcast<<<dim3(FFNN / 32, EE / 32), dim3(32, 8), 0, stream>>>(ffn_W1, W1T, EE, FFNN, EE);
  transcast<<<dim3(EE / 32, FFNN / 32), dim3(32, 8), 0, stream>>>(ffn_W2, W2T, FFNN, EE, FFNN);
  castx_kernel<<<(TBR * FINP) / 256, 256, 0, stream>>>(x, xb);

  // 1) encoder
  gemm_bf16<true, false, false, true, true><<<dim3(EE / 128, TBR / 128), 256, 0, stream>>>(
      xb, WencT, tx32, txb, enc_b, yenc_b, y, yenc_W, TBR, EE, FINP);
  // 2) fused QKV
  gemm_bf16<false, false, false, false, true><<<dim3(1536 / 128, TBR / 128), 256, 0, stream>>>(
      txb, WqkvT, nullptr, qkvb, nullptr, nullptr, nullptr, nullptr, TBR, 1536, EE);
  // 3) V transpose (s-axis swizzled for PV)
  vtrans<<<dim3(SEP / 64, NHH, BB), 256, 0, stream>>>(qkvb, vt);
  // 4) flash attention (XCD-aware grid: id%8 == hb%8)
  attn_mfma<<<dim3(NHH * BB, SEP / 64), 256, 0, stream>>>(qkvb, vt, aob);
  // 5) Wo projection
  gemm_bf16<false, false, false, true, false><<<dim3(EE / 128, TBR / 128), 256, 0, stream>>>(
      aob, WoT, aop, nullptr, nullptr, nullptr, nullptr, nullptr, TBR, EE, EE);
  // 6) LN1
  ln_k<true><<<TBR, 256, 0, stream>>>(tx32, aop, ln1_g, ln1_b, z32, zb);
  // 7) FFN1
  gemm_bf16<false, true, true, false, true><<<dim3(FFNN / 128, TBR / 128), 256, 0, stream>>>(
      zb, W1T, nullptr, ff1b, ffn_b1, nullptr, nullptr, nullptr, TBR, FFNN, EE);
  // 8) FFN2
  gemm_bf16<false, true, false, true, false><<<dim3(EE / 128, TBR / 128), 256, 0, stream>>>(
      ff1b, W2T, ff2, nullptr, ffn_b2, nullptr, nullptr, nullptr, TBR, EE, FFNN);
  // 9) LN2
  ln_k<false><<<TBR, 256, 0, stream>>>(z32, ff2, ln2_g, ln2_b, outb, nullptr);
  // 10) decoder
  pool1<<<dim3(32, 16), 256, 0, stream>>>(outb, pp);
  pool2<<<32, 256, 0, stream>>>(pp, pooled);
  dec1<<<dim3(4, BB), 256, 0, stream>>>(pooled, dec_W, pd);
  dec2<<<64, 256, 0, stream>>>(pd, dec_b, dh);
  hgemm_split<128><<<dim3(50, 8), 256, 0, stream>>>(dh, hw1, hgp, FIN * HHN);
  hg_reduce<<<800, 256, 0, stream>>>(hgp, w1g, BB * FIN * HHN, 8);
  hgemm_split<64><<<dim3(5, 16), 256, 0, stream>>>(dh, hw2, hgp, HHN * NOUTN);
  hg_reduce<<<80, 256, 0, stream>>>(hgp, w2g, BB * HHN * NOUTN, 16);
  hgemm_split<64><<<dim3(1, 16), 256, 0, stream>>>(dh, hb1, hgp, HHN);
  hg_reduce<<<8, 256, 0, stream>>>(hgp, b1g, BB * HHN, 16);
  hgemm_split<64><<<dim3(1, 16), 256, 0, stream>>>(dh, hb2, hgp, NOUTN);
  hg_reduce<<<1, 256, 0, stream>>>(hgp, b2g, BB * NOUTN, 16);
  // 11) generated per-batch MLP on eval tokens
  eval1_kernel<<<dim3(HHN / 256, EVALN / 8, BB), 256, 0, stream>>>(x, w1g, b1g, h1);
  eval2_kernel<<<dim3(EVALN / 64, BB), 256, 0, stream>>>(h1, w2g, b2g, outp);
}

// Round 5
// 851.932 us; speedup vs baseline: 6.0096x; 1.0137x over previous
//
#include <hip/hip_runtime.h>
#include <math.h>

// Problem constants: S=2048, B=16, F=100, E=512, NH=8, DH=64, FF=2048,
// DEC=1024, H=512, NOUT=10, sep=1024 (structural).
#define SEP   1024
#define EVALN 1024
#define BB    16
#define FIN   100
#define FINP  128          // F padded to 128 for bf16 GEMM (zeros)
#define EE    512
#define NHH   8
#define DHH   64
#define FFNN  2048
#define DECN  1024
#define HHN   512
#define NOUTN 10
#define TBR   (SEP * BB)   // 16384 token rows
#define MB    (1024u * 1024u)

typedef short  s16x8 __attribute__((ext_vector_type(8)));
typedef float  f32x4 __attribute__((ext_vector_type(4)));

__device__ __forceinline__ unsigned short f2b(float f) {
  union { float f; unsigned int u; } v; v.f = f;
  unsigned int u = v.u;
  return (unsigned short)((u + 0x7fffu + ((u >> 16) & 1u)) >> 16);
}

__device__ __forceinline__ float nan2num(float v) {
  if (isnan(v)) return 0.f;
  if (isinf(v)) return v > 0.f ? 3.4028234663852886e38f : -3.4028234663852886e38f;
  return v;
}

// async global->LDS, 16 B per lane; LDS dest = wave-uniform base + lane*16.
__device__ __forceinline__ void gld16(const void* g, void* l) {
  __builtin_amdgcn_global_load_lds(
      (const __attribute__((address_space(1))) unsigned int*)g,
      (__attribute__((address_space(3))) unsigned int*)l, 16, 0, 0);
}

// ---------------------------------------------------------------------------
// Weight transpose+cast: W[K][N] f32 -> Wt[N][Kp] bf16 (zero-padded K..Kp).
// ---------------------------------------------------------------------------
__global__ __launch_bounds__(256)
void transcast(const float* __restrict__ W, unsigned short* __restrict__ Wt,
               int K, int N, int Kp) {
  __shared__ float t[32][33];
  const int n0 = blockIdx.x * 32, k0 = blockIdx.y * 32;
  const int tx = threadIdx.x, ty = threadIdx.y;
#pragma unroll
  for (int r = 0; r < 4; ++r) {
    const int k = k0 + ty + r * 8;
    t[ty + r * 8][tx] = (k < K) ? W[(size_t)k * N + n0 + tx] : 0.f;
  }
  __syncthreads();
#pragma unroll
  for (int r = 0; r < 4; ++r) {
    const int n = n0 + ty + r * 8;
    Wt[(size_t)n * Kp + k0 + tx] = f2b(t[tx][ty + r * 8]);
  }
}

// x[:sep] f32 [16384][100] -> xb bf16 [16384][128] (zero-padded)
__global__ __launch_bounds__(256)
void castx_kernel(const float* __restrict__ x, unsigned short* __restrict__ xb) {
  const int idx = blockIdx.x * 256 + threadIdx.x;
  const int m = idx >> 7, f = idx & 127;
  xb[idx] = (f < FIN) ? f2b(x[(size_t)m * FIN + f]) : (unsigned short)0;
}

// ---------------------------------------------------------------------------
// bf16 MFMA GEMM: C[M,N] = A[M,K](bf16) @ Bt[N,K](bf16)^T  + epilogue.
// m97-style: global_load_lds width=16 staging into UNPADDED LDS (64 B rows,
// BK=32) with XOR chunk swizzle phys = q ^ ((row>>2)&3):
//  - staging lane's logical chunk = (lane&3) ^ (lane>>4)  (row-independent)
//  - fragment ds_read_b128 lands 2 lanes/bank (free, m136)
// 2-barrier K-loop: issue DMA -> barrier (vmcnt drain) -> ds_read+mfma -> barrier.
// ---------------------------------------------------------------------------
template <bool YENC, bool BIAS, bool RELU, bool OF32, bool OB16>
__global__ __launch_bounds__(256)
void gemm_bf16(const unsigned short* __restrict__ A,
               const unsigned short* __restrict__ Bt,
               float* __restrict__ C32, unsigned short* __restrict__ C16,
               const float* __restrict__ bias, const float* __restrict__ yb2,
               const float* __restrict__ yvec, const float* __restrict__ yW,
               int M, int N, int K) {
  __shared__ unsigned short As[128 * 32];  // [row][chunk-swizzled 4x8 bf16]
  __shared__ unsigned short Bs[128 * 32];
  const int tid = threadIdx.x;
  const int wave = tid >> 6, lane = tid & 63;
  const int q = lane >> 4, c = lane & 15;
  const int wm = wave >> 1, wn = wave & 1;
  const int m0 = blockIdx.y * 128, n0 = blockIdx.x * 128;
  // staging: inst j of this wave covers rows wave*32+j*16 .. +15 (16 rows x 64B)
  const int srow = lane >> 2;                  // row within 16
  const int qlog = (lane & 3) ^ (lane >> 4);   // logical k-chunk this lane fetches
  const int rA0 = wave * 32 + srow;
  const int rA1 = rA0 + 16;
  unsigned short* lA0 = As + wave * 1024;      // bytes: wave*2048
  unsigned short* lA1 = As + wave * 1024 + 512;
  unsigned short* lB0 = Bs + wave * 1024;
  unsigned short* lB1 = Bs + wave * 1024 + 512;
  const unsigned short* gA0 = A + (size_t)(m0 + rA0) * K + qlog * 8;
  const unsigned short* gA1 = A + (size_t)(m0 + rA1) * K + qlog * 8;
  const unsigned short* gB0 = Bt + (size_t)(n0 + rA0) * K + qlog * 8;
  const unsigned short* gB1 = Bt + (size_t)(n0 + rA1) * K + qlog * 8;

  f32x4 acc[4][4];
#pragma unroll
  for (int i = 0; i < 4; ++i)
#pragma unroll
    for (int j = 0; j < 4; ++j) acc[i][j] = (f32x4){0.f, 0.f, 0.f, 0.f};

  // fragment LDS offsets (shorts): row m = wm*64+mi*16+c, phys chunk q^(c>>2)
  const int pchunk = (q ^ (c >> 2)) * 8;
  const int aoff = (wm * 64 + c) * 32 + pchunk;
  const int boff = (wn * 64 + c) * 32 + pchunk;

  for (int k0 = 0; k0 < K; k0 += 32) {
    gld16(gA0 + k0, lA0);
    gld16(gA1 + k0, lA1);
    gld16(gB0 + k0, lB0);
    gld16(gB1 + k0, lB1);
    __syncthreads();  // vmcnt(0) drain: tiles resident
    s16x8 af[4], bf[4];
#pragma unroll
    for (int mi = 0; mi < 4; ++mi)
      af[mi] = *(const s16x8*)&As[aoff + mi * 16 * 32];
#pragma unroll
    for (int ni = 0; ni < 4; ++ni)
      bf[ni] = *(const s16x8*)&Bs[boff + ni * 16 * 32];
#pragma unroll
    for (int mi = 0; mi < 4; ++mi)
#pragma unroll
      for (int ni = 0; ni < 4; ++ni)
        acc[mi][ni] = __builtin_amdgcn_mfma_f32_16x16x32_bf16(
            af[mi], bf[ni], acc[mi][ni], 0, 0, 0);
    __syncthreads();  // readers done before next iter's DMA overwrites
  }

  float bb[4], yw[4];
#pragma unroll
  for (int ni = 0; ni < 4; ++ni) {
    const int n = n0 + wn * 64 + ni * 16 + c;
    float t = 0.f;
    if (BIAS) t = bias[n];
    if (YENC) t = bias[n] + yb2[n];
    bb[ni] = t;
    yw[ni] = YENC ? yW[n] : 0.f;
  }
#pragma unroll
  for (int mi = 0; mi < 4; ++mi) {
#pragma unroll
    for (int r = 0; r < 4; ++r) {
      const int m = m0 + wm * 64 + mi * 16 + q * 4 + r;
      const float yv = YENC ? yvec[m] : 0.f;
#pragma unroll
      for (int ni = 0; ni < 4; ++ni) {
        const int n = n0 + wn * 64 + ni * 16 + c;
        float val = acc[mi][ni][r] + bb[ni];
        if (YENC) val = fmaf(yv, yw[ni], val);
        if (RELU) val = fmaxf(val, 0.f);
        if (OF32) C32[(size_t)m * N + n] = val;
        if (OB16) C16[(size_t)m * N + n] = f2b(val);
      }
    }
  }
}

// ---------------------------------------------------------------------------
// V transpose for PV B-operand, with the s-axis PV swizzle baked in:
// within each 64-s block, phys position p holds logical s = 16*(p&3)+(p>>2).
// P is written with the same permutation, so PV's MFMA k-sum is exact.
// ---------------------------------------------------------------------------
__global__ __launch_bounds__(256)
void vtrans(const unsigned short* __restrict__ qkv, unsigned short* __restrict__ vt) {
  __shared__ unsigned short t[64][72];   // t[d][s_local]
  const int s0 = blockIdx.x * 64;
  const int h = blockIdx.y, b = blockIdx.z;
  const int tid = threadIdx.x;
  const int r = tid >> 2, o = (tid & 3) * 16;
  const unsigned short* g =
      qkv + ((size_t)(s0 + r) * BB + b) * 1536 + 1024 + h * 64 + o;
  unsigned short tmp[16];
  *(uint4*)tmp = *(const uint4*)g;
  *(uint4*)(tmp + 8) = *(const uint4*)(g + 8);
#pragma unroll
  for (int i = 0; i < 16; ++i) t[o + i][r] = tmp[i];   // t[d][s] = V[s][d]
  __syncthreads();
  unsigned short tmp2[16];
#pragma unroll
  for (int i = 0; i < 16; ++i) {
    const int p = o + i;
    tmp2[i] = t[r][16 * (p & 3) + (p >> 2)];
  }
  unsigned short* out =
      vt + ((size_t)(b * NHH + h) * 64 + r) * 1024 + s0 + o;
  *(uint4*)out = *(const uint4*)&tmp2[0];
  *(uint4*)(out + 8) = *(const uint4*)&tmp2[8];
}

// ---------------------------------------------------------------------------
// Flash attention, bf16 MFMA.  Grid (hb=128, t0/64=16): id%8 = hb%8 so all
// t0-blocks of one (b,h) share an XCD -> K/V L2-resident.  Per s-tile:
// prefetch next K/V to regs, QK mfma, online softmax, packed ds_write_b64 of
// swizzled P (wave-private, NO barrier), PV mfma, 2 barriers total.
// ---------------------------------------------------------------------------
__global__ __launch_bounds__(256)
void attn_mfma(const unsigned short* __restrict__ qkv,
               const unsigned short* __restrict__ vt,
               unsigned short* __restrict__ aob) {
  __shared__ unsigned short Qs[64][72];
  __shared__ unsigned short Ks[64][72];
  __shared__ unsigned short Vts[64][72];
  __shared__ unsigned short Pls[4][16][72];
  const int tid = threadIdx.x;
  const int w = tid >> 6, lane = tid & 63;
  const int q = lane >> 4, c = lane & 15;
  const int hb = blockIdx.x;
  const int h = hb & (NHH - 1), b = hb >> 3;
  const int t0 = blockIdx.y * 64;
  const int bh = b * NHH + h;
  const int sr = tid >> 2, so = (tid & 3) * 16;

  {
    const unsigned short* g =
        qkv + ((size_t)(t0 + sr) * BB + b) * 1536 + h * 64 + so;
    *(uint4*)&Qs[sr][so] = *(const uint4*)g;
    *(uint4*)&Qs[sr][so + 8] = *(const uint4*)(g + 8);
  }
  __syncthreads();
  s16x8 aq[2];
  aq[0] = *(const s16x8*)&Qs[w * 16 + c][q * 8];
  aq[1] = *(const s16x8*)&Qs[w * 16 + c][32 + q * 8];

  float m_s[4], l_s[4];
  f32x4 oacc[4];
#pragma unroll
  for (int r = 0; r < 4; ++r) { m_s[r] = -3.0e38f; l_s[r] = 0.f; }
#pragma unroll
  for (int dt = 0; dt < 4; ++dt) oacc[dt] = (f32x4){0.f, 0.f, 0.f, 0.f};

  uint4 kr0, kr1, vr0, vr1;
  {
    const unsigned short* gk =
        qkv + ((size_t)sr * BB + b) * 1536 + 512 + h * 64 + so;
    kr0 = *(const uint4*)gk; kr1 = *(const uint4*)(gk + 8);
    const unsigned short* gv = vt + ((size_t)bh * 64 + sr) * 1024 + so;
    vr0 = *(const uint4*)gv; vr1 = *(const uint4*)(gv + 8);
  }
  *(uint4*)&Ks[sr][so] = kr0; *(uint4*)&Ks[sr][so + 8] = kr1;
  *(uint4*)&Vts[sr][so] = vr0; *(uint4*)&Vts[sr][so + 8] = vr1;
  __syncthreads();

  for (int s0 = 0; s0 < SEP; s0 += 64) {
    const bool more = (s0 + 64 < SEP);
    if (more) {
      const unsigned short* gk =
          qkv + ((size_t)(s0 + 64 + sr) * BB + b) * 1536 + 512 + h * 64 + so;
      kr0 = *(const uint4*)gk; kr1 = *(const uint4*)(gk + 8);
      const unsigned short* gv =
          vt + ((size_t)bh * 64 + sr) * 1024 + s0 + 64 + so;
      vr0 = *(const uint4*)gv; vr1 = *(const uint4*)(gv + 8);
    }
    f32x4 sacc[4];
#pragma unroll
    for (int ch = 0; ch < 4; ++ch) sacc[ch] = (f32x4){0.f, 0.f, 0.f, 0.f};
#pragma unroll
    for (int ch = 0; ch < 4; ++ch) {
#pragma unroll
      for (int kh = 0; kh < 2; ++kh) {
        s16x8 bk = *(const s16x8*)&Ks[ch * 16 + c][kh * 32 + q * 8];
        sacc[ch] = __builtin_amdgcn_mfma_f32_16x16x32_bf16(
            aq[kh], bk, sacc[ch], 0, 0, 0);
      }
    }
    float rmax[4];
#pragma unroll
    for (int r = 0; r < 4; ++r) {
      float mx = -3.0e38f;
#pragma unroll
      for (int ch = 0; ch < 4; ++ch) mx = fmaxf(mx, sacc[ch][r] * 0.125f);
      rmax[r] = mx;
    }
#pragma unroll
    for (int mask = 1; mask < 16; mask <<= 1)
#pragma unroll
      for (int r = 0; r < 4; ++r)
        rmax[r] = fmaxf(rmax[r], __shfl_xor(rmax[r], mask));
    float alpha[4], rsum[4];
    float p[4][4];
#pragma unroll
    for (int r = 0; r < 4; ++r) {
      const float mnew = fmaxf(m_s[r], rmax[r]);
      alpha[r] = __expf(m_s[r] - mnew);
      float sum = 0.f;
#pragma unroll
      for (int ch = 0; ch < 4; ++ch) {
        const float pv = __expf(sacc[ch][r] * 0.125f - mnew);
        p[ch][r] = pv;
        sum += pv;
      }
      rsum[r] = sum;
      m_s[r] = mnew;
    }
#pragma unroll
    for (int mask = 1; mask < 16; mask <<= 1)
#pragma unroll
      for (int r = 0; r < 4; ++r) rsum[r] += __shfl_xor(rsum[r], mask);
#pragma unroll
    for (int r = 0; r < 4; ++r) l_s[r] = l_s[r] * alpha[r] + rsum[r];
#pragma unroll
    for (int dt = 0; dt < 4; ++dt)
#pragma unroll
      for (int r = 0; r < 4; ++r) oacc[dt][r] *= alpha[r];
#pragma unroll
    for (int r = 0; r < 4; ++r) {
      uint2 pk;
      pk.x = (unsigned)f2b(p[0][r]) | ((unsigned)f2b(p[1][r]) << 16);
      pk.y = (unsigned)f2b(p[2][r]) | ((unsigned)f2b(p[3][r]) << 16);
      *(uint2*)&Pls[w][q * 4 + r][c * 4] = pk;
    }
#pragma unroll
    for (int kh = 0; kh < 2; ++kh) {
      s16x8 ap = *(const s16x8*)&Pls[w][c][kh * 32 + q * 8];
#pragma unroll
      for (int dt = 0; dt < 4; ++dt) {
        s16x8 bv = *(const s16x8*)&Vts[dt * 16 + c][kh * 32 + q * 8];
        oacc[dt] = __builtin_amdgcn_mfma_f32_16x16x32_bf16(
            ap, bv, oacc[dt], 0, 0, 0);
      }
    }
    __syncthreads();
    if (more) {
      *(uint4*)&Ks[sr][so] = kr0; *(uint4*)&Ks[sr][so + 8] = kr1;
      *(uint4*)&Vts[sr][so] = vr0; *(uint4*)&Vts[sr][so + 8] = vr1;
      __syncthreads();
    }
  }
  float inv[4];
#pragma unroll
  for (int r = 0; r < 4; ++r) inv[r] = 1.f / l_s[r];
#pragma unroll
  for (int dt = 0; dt < 4; ++dt) {
#pragma unroll
    for (int r = 0; r < 4; ++r) {
      const int m = t0 + w * 16 + q * 4 + r;
      aob[((size_t)m * BB + b) * EE + h * 64 + dt * 16 + c] =
          f2b(oacc[dt][r] * inv[r]);
    }
  }
}

// ---------------------------------------------------------------------------
// LayerNorm: o = LN(a + r) * g + be.  Optionally also emit bf16 copy.
// ---------------------------------------------------------------------------
template <bool B16>
__global__ __launch_bounds__(256)
void ln_k(const float* __restrict__ a, const float* __restrict__ r_,
          const float* __restrict__ g, const float* __restrict__ be,
          float* __restrict__ o32, unsigned short* __restrict__ o16) {
  __shared__ float ss[4], sqs[4];
  const int row = blockIdx.x;
  const int tid = threadIdx.x;
  const size_t base = (size_t)row * EE;
  const float x0 = a[base + tid] + r_[base + tid];
  const float x1 = a[base + tid + 256] + r_[base + tid + 256];
  float s = x0 + x1;
  float sq = x0 * x0 + x1 * x1;
#pragma unroll
  for (int off = 32; off >= 1; off >>= 1) {
    s += __shfl_xor(s, off);
    sq += __shfl_xor(sq, off);
  }
  const int wid = tid >> 6;
  if ((tid & 63) == 0) { ss[wid] = s; sqs[wid] = sq; }
  __syncthreads();
  s = ss[0] + ss[1] + ss[2] + ss[3];
  sq = sqs[0] + sqs[1] + sqs[2] + sqs[3];
  const float mean = s * (1.f / 512.f);
  const float var = sq * (1.f / 512.f) - mean * mean;
  const float rstd = rsqrtf(fmaxf(var, 0.f) + 1e-5f);
  const float v0 = (x0 - mean) * rstd * g[tid] + be[tid];
  const float v1 = (x1 - mean) * rstd * g[tid + 256] + be[tid + 256];
  o32[base + tid] = v0;
  o32[base + tid + 256] = v1;
  if (B16) {
    o16[base + tid] = f2b(v0);
    o16[base + tid + 256] = f2b(v1);
  }
}

// ---------------------------------------------------------------------------
// Decoder tail — K-split partials + reduce (latency-bound fixes).
// ---------------------------------------------------------------------------
__global__ __launch_bounds__(256)
void pool1(const float* __restrict__ outb, float* __restrict__ pp) {
  const int i = blockIdx.x * 256 + threadIdx.x;      // < 8192
  const int ts = blockIdx.y;
  const float* p = outb + (size_t)ts * 64 * (BB * EE) + i;
  float s0 = 0.f, s1 = 0.f, s2 = 0.f, s3 = 0.f;
  for (int t = 0; t < 64; t += 4) {
    s0 += p[(size_t)(t + 0) * (BB * EE)];
    s1 += p[(size_t)(t + 1) * (BB * EE)];
    s2 += p[(size_t)(t + 2) * (BB * EE)];
    s3 += p[(size_t)(t + 3) * (BB * EE)];
  }
  pp[ts * (BB * EE) + i] = (s0 + s1) + (s2 + s3);
}

__global__ __launch_bounds__(256)
void pool2(const float* __restrict__ pp, float* __restrict__ pooled) {
  const int i = blockIdx.x * 256 + threadIdx.x;
  float s = 0.f;
#pragma unroll
  for (int ts = 0; ts < 16; ++ts) s += pp[ts * (BB * EE) + i];
  pooled[i] = s * (1.f / (float)SEP);
}

__global__ __launch_bounds__(256)
void dec1(const float* __restrict__ pooled, const float* __restrict__ dW,
          float* __restrict__ pd) {
  __shared__ float ps[128];
  const int ks = blockIdx.x, b = blockIdx.y;
  const int tid = threadIdx.x;
  if (tid < 128) ps[tid] = pooled[b * EE + ks * 128 + tid];
  __syncthreads();
  const int n = tid * 4;
  float4 acc = {0.f, 0.f, 0.f, 0.f};
  for (int kk = 0; kk < 128; kk += 4) {
    const float4 p4 = *(const float4*)&ps[kk];
#pragma unroll
    for (int i = 0; i < 4; ++i) {
      const float4 w4 = *(const float4*)&dW[(size_t)(ks * 128 + kk + i) * DECN + n];
      const float pv = (i == 0) ? p4.x : (i == 1) ? p4.y : (i == 2) ? p4.z : p4.w;
      acc.x = fmaf(pv, w4.x, acc.x); acc.y = fmaf(pv, w4.y, acc.y);
      acc.z = fmaf(pv, w4.z, acc.z); acc.w = fmaf(pv, w4.w, acc.w);
    }
  }
  *(float4*)&pd[(size_t)(ks * BB + b) * DECN + n] = acc;
}

__global__ __launch_bounds__(256)
void dec2(const float* __restrict__ pd, const float* __restrict__ db,
          float* __restrict__ dh) {
  const int idx = blockIdx.x * 256 + threadIdx.x;    // < 16384
  const int b = idx >> 10, n = idx & 1023;
  float s = db[n];
#pragma unroll
  for (int ks = 0; ks < 4; ++ks) s += pd[(size_t)(ks * BB + b) * DECN + n];
  dh[idx] = fmaxf(s, 0.f);
}

template <int KL>
__global__ __launch_bounds__(256)
void hgemm_split(const float* __restrict__ dh, const float* __restrict__ W,
                 float* __restrict__ part, int N) {
  __shared__ float dhs[16][KL];
  const int tid = threadIdx.x;
  const int n0 = blockIdx.x * 1024;
  const int k0 = blockIdx.y * KL;
  for (int i = tid; i < 16 * (KL / 4); i += 256) {
    const int b = i / (KL / 4), kq = i % (KL / 4);
    *(float4*)&dhs[b][kq * 4] = *(const float4*)&dh[b * DECN + k0 + kq * 4];
  }
  __syncthreads();
  float* pb = part + (size_t)blockIdx.y * 16 * N;
  if ((N & 3) == 0) {
    const int n = n0 + tid * 4;
    if (n + 3 < N) {
      float4 acc[16];
#pragma unroll
      for (int b = 0; b < 16; ++b) acc[b] = (float4){0.f, 0.f, 0.f, 0.f};
      for (int kk = 0; kk < KL; kk += 4) {
        float4 w4[4];
#pragma unroll
        for (int i = 0; i < 4; ++i)
          w4[i] = *(const float4*)&W[(size_t)(k0 + kk + i) * N + n];
#pragma unroll
        for (int b = 0; b < 16; ++b) {
          const float4 d4 = *(const float4*)&dhs[b][kk];
          acc[b].x = fmaf(d4.x, w4[0].x, acc[b].x);
          acc[b].y = fmaf(d4.x, w4[0].y, acc[b].y);
          acc[b].z = fmaf(d4.x, w4[0].z, acc[b].z);
          acc[b].w = fmaf(d4.x, w4[0].w, acc[b].w);
          acc[b].x = fmaf(d4.y, w4[1].x, acc[b].x);
          acc[b].y = fmaf(d4.y, w4[1].y, acc[b].y);
          acc[b].z = fmaf(d4.y, w4[1].z, acc[b].z);
          acc[b].w = fmaf(d4.y, w4[1].w, acc[b].w);
          acc[b].x = fmaf(d4.z, w4[2].x, acc[b].x);
          acc[b].y = fmaf(d4.z, w4[2].y, acc[b].y);
          acc[b].z = fmaf(d4.z, w4[2].z, acc[b].z);
          acc[b].w = fmaf(d4.z, w4[2].w, acc[b].w);
          acc[b].x = fmaf(d4.w, w4[3].x, acc[b].x);
          acc[b].y = fmaf(d4.w, w4[3].y, acc[b].y);
          acc[b].z = fmaf(d4.w, w4[3].z, acc[b].z);
          acc[b].w = fmaf(d4.w, w4[3].w, acc[b].w);
        }
      }
#pragma unroll
      for (int b = 0; b < 16; ++b) *(float4*)&pb[(size_t)b * N + n] = acc[b];
    }
  } else {
    const int n = n0 + tid;
    if (n < N) {
      float acc[16];
#pragma unroll
      for (int b = 0; b < 16; ++b) acc[b] = 0.f;
      for (int kk = 0; kk < KL; ++kk) {
        const float w = W[(size_t)(k0 + kk) * N + n];
#pragma unroll
        for (int b = 0; b < 16; ++b) acc[b] = fmaf(dhs[b][kk], w, acc[b]);
      }
#pragma unroll
      for (int b = 0; b < 16; ++b) pb[(size_t)b * N + n] = acc[b];
    }
  }
}

__global__ __launch_bounds__(256)
void hg_reduce(const float* __restrict__ part, float* __restrict__ out,
               int total, int S) {
  const int i4 = (blockIdx.x * 256 + threadIdx.x) * 4;
  if (i4 >= total) return;
  float4 s = *(const float4*)&part[i4];
  for (int p = 1; p < S; ++p) {
    const float4 v = *(const float4*)&part[(size_t)p * total + i4];
    s.x += v.x; s.y += v.y; s.z += v.z; s.w += v.w;
  }
  *(float4*)&out[i4] = s;
}

// h1[e,b,h] = relu(nan2num(x[sep+e,b,:]) @ w1[b,:,h] + b1[b,h])
__global__ __launch_bounds__(256)
void eval1_kernel(const float* __restrict__ x, const float* __restrict__ w1,
                  const float* __restrict__ b1, float* __restrict__ h1) {
  __shared__ float xs[8][100];
  const int b = blockIdx.z;
  const int e0 = blockIdx.y << 3;
  const int hcol = blockIdx.x * 256 + threadIdx.x;
  for (int i = threadIdx.x; i < 800; i += 256) {
    const int ee = i / 100, f = i - ee * 100;
    xs[ee][f] = nan2num(x[((size_t)(SEP + e0 + ee) * BB + b) * FIN + f]);
  }
  __syncthreads();
  float acc[8];
#pragma unroll
  for (int i = 0; i < 8; ++i) acc[i] = 0.f;
  for (int f = 0; f < FIN; ++f) {
    const float w = w1[(size_t)b * (FIN * HHN) + (size_t)f * HHN + hcol];
#pragma unroll
    for (int ee = 0; ee < 8; ++ee) acc[ee] = fmaf(xs[ee][f], w, acc[ee]);
  }
  const float bias = b1[b * HHN + hcol];
#pragma unroll
  for (int ee = 0; ee < 8; ++ee)
    h1[((size_t)(e0 + ee) * BB + b) * HHN + hcol] = fmaxf(acc[ee] + bias, 0.f);
}

// eval2: per-(b, 64 rows) block, w2 staged in LDS, 4-way K-split + LDS reduce
__global__ __launch_bounds__(256)
void eval2_kernel(const float* __restrict__ h1, const float* __restrict__ w2,
                  const float* __restrict__ b2, float* __restrict__ outp) {
  __shared__ float w2s[10][512];
  __shared__ float red[4][64][10];
  const int b = blockIdx.y;
  const int e0 = blockIdx.x * 64;
  const int tid = threadIdx.x;
  const int r = tid & 63, ks = tid >> 6;
  for (int i = tid; i < 5120; i += 256) {
    const int o = i >> 9, k = i & 511;
    w2s[o][k] = w2[(size_t)b * (HHN * NOUTN) + k * NOUTN + o];
  }
  __syncthreads();
  const int eb = (e0 + r) * BB + b;
  const float* hp = h1 + (size_t)eb * HHN + ks * 128;
  float acc[10];
#pragma unroll
  for (int o = 0; o < 10; ++o) acc[o] = 0.f;
  for (int kk = 0; kk < 128; kk += 4) {
    const float4 h4 = *(const float4*)&hp[kk];
#pragma unroll
    for (int o = 0; o < 10; ++o) {
      const float4 w4 = *(const float4*)&w2s[o][ks * 128 + kk];
      acc[o] = fmaf(h4.x, w4.x, acc[o]);
      acc[o] = fmaf(h4.y, w4.y, acc[o]);
      acc[o] = fmaf(h4.z, w4.z, acc[o]);
      acc[o] = fmaf(h4.w, w4.w, acc[o]);
    }
  }
#pragma unroll
  for (int o = 0; o < 10; ++o) red[ks][r][o] = acc[o];
  __syncthreads();
  if (ks == 0) {
#pragma unroll
    for (int o = 0; o < 10; ++o)
      outp[(size_t)eb * NOUTN + o] = red[0][r][o] + red[1][r][o] +
                                     red[2][r][o] + red[3][r][o] +
                                     b2[b * NOUTN + o];
  }
}

// ---------------------------------------------------------------------------
extern "C" void kernel_launch(void* const* d_in, const int* in_sizes, int n_in,
                              void* d_out, int out_size, void* d_ws, size_t ws_size,
                              hipStream_t stream) {
  const float* x      = (const float*)d_in[0];
  const float* y      = (const float*)d_in[1];
  const float* enc_W  = (const float*)d_in[2];
  const float* enc_b  = (const float*)d_in[3];
  const float* yenc_W = (const float*)d_in[4];
  const float* yenc_b = (const float*)d_in[5];
  const float* Wq     = (const float*)d_in[6];
  const float* Wk     = (const float*)d_in[7];
  const float* Wv     = (const float*)d_in[8];
  const float* Wo     = (const float*)d_in[9];
  const float* ln1_g  = (const float*)d_in[10];
  const float* ln1_b  = (const float*)d_in[11];
  const float* ln2_g  = (const float*)d_in[12];
  const float* ln2_b  = (const float*)d_in[13];
  const float* ffn_W1 = (const float*)d_in[14];
  const float* ffn_b1 = (const float*)d_in[15];
  const float* ffn_W2 = (const float*)d_in[16];
  const float* ffn_b2 = (const float*)d_in[17];
  const float* dec_W  = (const float*)d_in[18];
  const float* dec_b  = (const float*)d_in[19];
  const float* hw1    = (const float*)d_in[20];
  const float* hb1    = (const float*)d_in[21];
  const float* hw2    = (const float*)d_in[22];
  const float* hb2    = (const float*)d_in[23];

  char* ws = (char*)d_ws;
  unsigned short* ff1b  = (unsigned short*)(ws + 0 * MB);    // 64MB (FFN1-FFN2)
  unsigned short* xb    = (unsigned short*)(ws + 0 * MB);    //  4MB (enc)
  float*          pp    = (float*)(ws + 0 * MB);             // 512KB (pool)
  float*          pd    = (float*)(ws + 1 * MB);             // 256KB (dec)
  float*          hgp   = (float*)(ws + 2 * MB);             // 26.2MB (head partials)
  unsigned short* txb   = (unsigned short*)(ws + 16 * MB);   // 16MB
  unsigned short* vt    = (unsigned short*)(ws + 32 * MB);   // 16MB
  unsigned short* aob   = (unsigned short*)(ws + 48 * MB);   // 16MB
  unsigned short* qkvb  = (unsigned short*)(ws + 64 * MB);   // 48MB
  float*          z32   = (float*)(ws + 64 * MB);            // 32MB (post-attn)
  unsigned short* zb    = (unsigned short*)(ws + 96 * MB);   // 16MB
  float*          tx32  = (float*)(ws + 112 * MB);           // 32MB
  float*          ff2   = (float*)(ws + 112 * MB);           // 32MB
  float*          aop   = (float*)(ws + 144 * MB);           // 32MB
  float*          outb  = (float*)(ws + 144 * MB);           // 32MB
  float*          h1    = (float*)(ws + 144 * MB);           // 32MB (eval)
  size_t wo_ = 176 * (size_t)MB;
  unsigned short* WencT = (unsigned short*)(ws + wo_); wo_ += (size_t)EE * FINP * 2;
  unsigned short* WqkvT = (unsigned short*)(ws + wo_); wo_ += (size_t)3 * EE * EE * 2;
  unsigned short* WoT   = (unsigned short*)(ws + wo_); wo_ += (size_t)EE * EE * 2;
  unsigned short* W1T   = (unsigned short*)(ws + wo_); wo_ += (size_t)FFNN * EE * 2;
  unsigned short* W2T   = (unsigned short*)(ws + wo_); wo_ += (size_t)EE * FFNN * 2;
  float* pooled = (float*)(ws + wo_); wo_ += (size_t)BB * EE * 4;
  float* dh     = (float*)(ws + wo_); wo_ += (size_t)BB * DECN * 4;
  float* w1g    = (float*)(ws + wo_); wo_ += (size_t)BB * FIN * HHN * 4;
  float* b1g    = (float*)(ws + wo_); wo_ += (size_t)BB * HHN * 4;
  float* w2g    = (float*)(ws + wo_); wo_ += (size_t)BB * HHN * NOUTN * 4;
  float* b2g    = (float*)(ws + wo_);
  float* outp = (float*)d_out;

  // 0) weight prep (bf16, transposed [N][K])
  transcast<<<dim3(EE / 32, FINP / 32), dim3(32, 8), 0, stream>>>(enc_W, WencT, FIN, EE, FINP);
  transcast<<<dim3(EE / 32, EE / 32), dim3(32, 8), 0, stream>>>(Wq, WqkvT, EE, EE, EE);
  transcast<<<dim3(EE / 32, EE / 32), dim3(32, 8), 0, stream>>>(Wk, WqkvT + (size_t)EE * EE, EE, EE, EE);
  transcast<<<dim3(EE / 32, EE / 32), dim3(32, 8), 0, stream>>>(Wv, WqkvT + (size_t)2 * EE * EE, EE, EE, EE);
  transcast<<<dim3(EE / 32, EE / 32), dim3(32, 8), 0, stream>>>(Wo, WoT, EE, EE, EE);
  transcast<<<dim3(FFNN / 32, EE / 32), dim3(32, 8), 0, stream>>>(ffn_W1, W1T, EE, FFNN, EE);
  transcast<<<dim3(EE / 32, FFNN / 32), dim3(32, 8), 0, stream>>>(ffn_W2, W2T, FFNN, EE, FFNN);
  castx_kernel<<<(TBR * FINP) / 256, 256, 0, stream>>>(x, xb);

  // 1) encoder
  gemm_bf16<true, false, false, true, true><<<dim3(EE / 128, TBR / 128), 256, 0, stream>>>(
      xb, WencT, tx32, txb, enc_b, yenc_b, y, yenc_W, TBR, EE, FINP);
  // 2) fused QKV
  gemm_bf16<false, false, false, false, true><<<dim3(1536 / 128, TBR / 128), 256, 0, stream>>>(
      txb, WqkvT, nullptr, qkvb, nullptr, nullptr, nullptr, nullptr, TBR, 1536, EE);
  // 3) V transpose (s-axis swizzled for PV)
  vtrans<<<dim3(SEP / 64, NHH, BB), 256, 0, stream>>>(qkvb, vt);
  // 4) flash attention (XCD-aware grid: id%8 == hb%8)
  attn_mfma<<<dim3(NHH * BB, SEP / 64), 256, 0, stream>>>(qkvb, vt, aob);
  // 5) Wo projection
  gemm_bf16<false, false, false, true, false><<<dim3(EE / 128, TBR / 128), 256, 0, stream>>>(
      aob, WoT, aop, nullptr, nullptr, nullptr, nullptr, nullptr, TBR, EE, EE);
  // 6) LN1
  ln_k<true><<<TBR, 256, 0, stream>>>(tx32, aop, ln1_g, ln1_b, z32, zb);
  // 7) FFN1
  gemm_bf16<false, true, true, false, true><<<dim3(FFNN / 128, TBR / 128), 256, 0, stream>>>(
      zb, W1T, nullptr, ff1b, ffn_b1, nullptr, nullptr, nullptr, TBR, FFNN, EE);
  // 8) FFN2
  gemm_bf16<false, true, false, true, false><<<dim3(EE / 128, TBR / 128), 256, 0, stream>>>(
      ff1b, W2T, ff2, nullptr, ffn_b2, nullptr, nullptr, nullptr, TBR, EE, FFNN);
  // 9) LN2
  ln_k<false><<<TBR, 256, 0, stream>>>(z32, ff2, ln2_g, ln2_b, outb, nullptr);
  // 10) decoder
  pool1<<<dim3(32, 16), 256, 0, stream>>>(outb, pp);
  pool2<<<32, 256, 0, stream>>>(pp, pooled);
  dec1<<<dim3(4, BB), 256, 0, stream>>>(pooled, dec_W, pd);
  dec2<<<64, 256, 0, stream>>>(pd, dec_b, dh);
  hgemm_split<128><<<dim3(50, 8), 256, 0, stream>>>(dh, hw1, hgp, FIN * HHN);
  hg_reduce<<<800, 256, 0, stream>>>(hgp, w1g, BB * FIN * HHN, 8);
  hgemm_split<64><<<dim3(5, 16), 256, 0, stream>>>(dh, hw2, hgp, HHN * NOUTN);
  hg_reduce<<<80, 256, 0, stream>>>(hgp, w2g, BB * HHN * NOUTN, 16);
  hgemm_split<64><<<dim3(1, 16), 256, 0, stream>>>(dh, hb1, hgp, HHN);
  hg_reduce<<<8, 256, 0, stream>>>(hgp, b1g, BB * HHN, 16);
  hgemm_split<64><<<dim3(1, 16), 256, 0, stream>>>(dh, hb2, hgp, NOUTN);
  hg_reduce<<<1, 256, 0, stream>>>(hgp, b2g, BB * NOUTN, 16);
  // 11) generated per-batch MLP on eval tokens
  eval1_kernel<<<dim3(HHN / 256, EVALN / 8, BB), 256, 0, stream>>>(x, w1g, b1g, h1);
  eval2_kernel<<<dim3(EVALN / 64, BB), 256, 0, stream>>>(h1, w2g, b2g, outp);
}